// Round 1
// baseline (8071.127 us; speedup 1.0000x reference)
//
#include <hip/hip_runtime.h>
#include <math.h>

#define NN 64
#define LDW 68      // padded LDS stride for matmul buffers (float4-aligned, 2-way banks)
#define LDC 65      // odd stride for cholesky buffer (conflict-free scalar column access)
#define LCH 32      // mean-scan chunk length
#define N1CAP 320   // smoother-cov backward tail cap

struct KP {
  const float *Y, *A, *b, *Q, *H, *c, *R, *pm0, *P0;
  float *out_mean, *out_cov, *out_ll;
  int *meta; float *metaF; double *ll_acc;
  float *fm;
  float *AT, *HT, *HA, *Hb;
  float *Fss, *Kss, *Sinvss, *Css, *CsTss, *pPss, *sPss, *Fpow, *Cpow32, *Cpow31, *uss;
  float *Pw2, *Pw4, *Pw8, *Pw16;
  float *u_chunk, *startstate, *ub_chunk, *endstate;
  float *ld_pref, *u_pref, *HPstash;
  float *fP, *pP, *Kp, *Sinvp, *Fp, *Cp, *CsTp;
  int N0cap, T, NC;
};

union F4 { float4 v; float f[4]; };

// ---------- helpers (assume blockDim.x == 256 unless noted) ----------

__device__ __forceinline__ void g2l(float* W, const float* G) {
  for (int e = threadIdx.x*4; e < 4096; e += 1024) {
    float4 v = *(const float4*)(G + e);
    *(float4*)(W + (e>>6)*LDW + (e&63)) = v;
  }
  __syncthreads();
}
__device__ __forceinline__ void l2g(float* G, const float* W) {
  for (int e = threadIdx.x*4; e < 4096; e += 1024)
    *(float4*)(G + e) = *(const float4*)(W + (e>>6)*LDW + (e&63));
  __syncthreads();
}
__device__ __forceinline__ void l2g_T(float* G, const float* W) {
  for (int e = threadIdx.x; e < 4096; e += 256)
    G[e] = W[(e&63)*LDW + (e>>6)];
  __syncthreads();
}
__device__ __forceinline__ void g2l65(float* C, const float* G) {
  for (int e = threadIdx.x*4; e < 4096; e += 1024) {
    F4 v; v.v = *(const float4*)(G + e);
    int base = (e>>6)*LDC + (e&63);
    C[base] = v.f[0]; C[base+1] = v.f[1]; C[base+2] = v.f[2]; C[base+3] = v.f[3];
  }
  __syncthreads();
}
__device__ __forceinline__ void copy65(float* W, const float* C) {
  for (int e = threadIdx.x; e < 4096; e += 256)
    W[(e>>6)*LDW + (e&63)] = C[(e>>6)*LDC + (e&63)];
  __syncthreads();
}
__device__ __forceinline__ void set_id(float* W) {
  for (int e = threadIdx.x; e < 4096; e += 256)
    W[(e>>6)*LDW + (e&63)] = ((e>>6) == (e&63)) ? 1.f : 0.f;
  __syncthreads();
}
__device__ __forceinline__ void sub_lg(float* D, const float* Wa, const float* G) {
  for (int e = threadIdx.x*4; e < 4096; e += 1024) {
    int base = (e>>6)*LDW + (e&63);
    F4 a, g; a.v = *(const float4*)(Wa + base); g.v = *(const float4*)(G + e);
    F4 o; o.f[0]=a.f[0]-g.f[0]; o.f[1]=a.f[1]-g.f[1]; o.f[2]=a.f[2]-g.f[2]; o.f[3]=a.f[3]-g.f[3];
    *(float4*)(D + base) = o.v;
  }
  __syncthreads();
}
__device__ __forceinline__ float red_max(float v, float* red) {
  red[threadIdx.x] = v; __syncthreads();
  #pragma unroll
  for (int s = 128; s > 0; s >>= 1) {
    if ((int)threadIdx.x < s) red[threadIdx.x] = fmaxf(red[threadIdx.x], red[threadIdx.x+s]);
    __syncthreads();
  }
  float r = red[0]; __syncthreads(); return r;
}
__device__ __forceinline__ float maxdiff_lg(const float* W, const float* G, float* red) {
  float m = 0.f;
  for (int e = threadIdx.x; e < 4096; e += 256)
    m = fmaxf(m, fabsf(W[(e>>6)*LDW + (e&63)] - G[e]));
  return red_max(m, red);
}
__device__ __forceinline__ float maxabs_l(const float* W, float* red) {
  float m = 0.f;
  for (int e = threadIdx.x; e < 4096; e += 256)
    m = fmaxf(m, fabsf(W[(e>>6)*LDW + (e&63)]));
  return red_max(m, red);
}

// D(=LDS,stride LDD) = [ADD +/-] op(A)*B ; A,B,ADD: LDS or global with given strides.
// MODE: 0 none, 1 D=ADD+P, 2 D=ADD-P. TRANSA: Aop[i][k]=A[k][i].
template<int TRANSA, int MODE, int LDD>
__device__ __forceinline__ void mm(float* __restrict__ D,
    const float* __restrict__ A, int lda,
    const float* __restrict__ B, int ldb,
    const float* __restrict__ ADD, int ldadd)
{
  const int tid = threadIdx.x;
  const int i0 = (tid >> 4) << 2, j0 = (tid & 15) << 2;
  float acc[4][4] = {};
  for (int k0 = 0; k0 < NN; k0 += 4) {
    F4 av[4], bv[4];
    #pragma unroll
    for (int u = 0; u < 4; ++u) {
      bv[u].v = *(const float4*)(B + (k0+u)*ldb + j0);
      av[u].v = TRANSA ? *(const float4*)(A + (k0+u)*lda + i0)
                       : *(const float4*)(A + (i0+u)*lda + k0);
    }
    #pragma unroll
    for (int kk = 0; kk < 4; ++kk) {
      #pragma unroll
      for (int di = 0; di < 4; ++di) {
        float a = TRANSA ? av[kk].f[di] : av[di].f[kk];
        #pragma unroll
        for (int dj = 0; dj < 4; ++dj) acc[di][dj] += a * bv[kk].f[dj];
      }
    }
  }
  #pragma unroll
  for (int di = 0; di < 4; ++di) {
    if (MODE == 0 && (LDD & 3) == 0) {
      F4 o;
      #pragma unroll
      for (int dj = 0; dj < 4; ++dj) o.f[dj] = acc[di][dj];
      *(float4*)(D + (i0+di)*LDD + j0) = o.v;
    } else {
      #pragma unroll
      for (int dj = 0; dj < 4; ++dj) {
        float v = acc[di][dj];
        if (MODE == 1) v = ADD[(i0+di)*ldadd + j0+dj] + v;
        if (MODE == 2) v = ADD[(i0+di)*ldadd + j0+dj] - v;
        D[(i0+di)*LDD + j0+dj] = v;
      }
    }
  }
  __syncthreads();
}

// left-looking Cholesky in stride-65 buffer; single wave (lanes 0..63). part[j]=log(L_jj)
__device__ __forceinline__ void chol65(float* Sm, float* part) {
  const int lane = threadIdx.x;
  if (lane < 64) {
    for (int j = 0; j < NN; ++j) {
      float acc = 0.f;
      if (lane >= j) {
        acc = Sm[lane*LDC + j];
        float a0=0.f,a1=0.f,a2=0.f,a3=0.f;
        int k = 0;
        for (; k+3 < j; k += 4) {
          a0 -= Sm[lane*LDC+k  ]*Sm[j*LDC+k  ];
          a1 -= Sm[lane*LDC+k+1]*Sm[j*LDC+k+1];
          a2 -= Sm[lane*LDC+k+2]*Sm[j*LDC+k+2];
          a3 -= Sm[lane*LDC+k+3]*Sm[j*LDC+k+3];
        }
        for (; k < j; ++k) a0 -= Sm[lane*LDC+k]*Sm[j*LDC+k];
        acc += (a0+a1)+(a2+a3);
      }
      float pv = (lane == j) ? sqrtf(fmaxf(acc, 1e-30f)) : 0.f;
      pv = __shfl(pv, j, 64);
      if (lane == j) { Sm[j*LDC+j] = pv; part[j] = logf(pv); }
      else if (lane > j) Sm[lane*LDC+j] = acc/pv;
    }
  }
  __syncthreads();
}
// triangular solves: L (stride LDC) ; X in/out (stride LDW), 64 RHS columns, 4 lanes/col.
__device__ __forceinline__ void tri_fwd(const float* L, float* X) {
  const int col = threadIdx.x >> 2, p = threadIdx.x & 3;
  for (int i = 0; i < NN; ++i) {
    float s = 0.f;
    for (int k = p; k < i; k += 4) s += L[i*LDC+k]*X[k*LDW+col];
    s += __shfl_xor(s, 1, 64); s += __shfl_xor(s, 2, 64);
    float xv = (X[i*LDW+col] - s) / L[i*LDC+i];
    if (p == 0) X[i*LDW+col] = xv;
  }
  __syncthreads();
}
__device__ __forceinline__ void tri_bwd(const float* L, float* X) {
  const int col = threadIdx.x >> 2, p = threadIdx.x & 3;
  for (int i = NN-1; i >= 0; --i) {
    float s = 0.f;
    for (int k = i+1+p; k < NN; k += 4) s += L[k*LDC+i]*X[k*LDW+col];
    s += __shfl_xor(s, 1, 64); s += __shfl_xor(s, 2, 64);
    float xv = (X[i*LDW+col] - s) / L[i*LDC+i];
    if (p == 0) X[i*LDW+col] = xv;
  }
  __syncthreads();
}
// y(LDS 64-vec) = Mg(64x64 row-major, stride 64)*x + addv (nullable). y may alias x.
__device__ __forceinline__ void matvec256(float* __restrict__ y, const float* __restrict__ Mg,
    const float* __restrict__ x, const float* __restrict__ addv, float* __restrict__ red) {
  const int r = threadIdx.x & 63, p = threadIdx.x >> 6;
  const int kb = p*16;
  float s = 0.f;
  #pragma unroll
  for (int q = 0; q < 4; ++q) {
    F4 mv; mv.v = *(const float4*)(Mg + r*NN + kb + q*4);
    s += mv.f[0]*x[kb+q*4] + mv.f[1]*x[kb+q*4+1] + mv.f[2]*x[kb+q*4+2] + mv.f[3]*x[kb+q*4+3];
  }
  red[p*64 + r] = s;
  __syncthreads();
  if (threadIdx.x < 64) {
    float t = red[r] + red[64+r] + red[128+r] + red[192+r];
    y[r] = t + (addv ? addv[r] : 0.f);
  }
  __syncthreads();
}

// ---------- kernels ----------

__global__ __launch_bounds__(256) void k0(KP P) {
  __shared__ __align__(16) float W0[LDW*NN];
  const int tid = threadIdx.x;
  for (int e = tid; e < 4096; e += 256) {
    int r = e>>6, cc = e&63;
    P.AT[e] = P.A[cc*64+r];
    P.HT[e] = P.H[cc*64+r];
  }
  if (tid < 64) {
    float s = 0.f;
    for (int k = 0; k < 64; ++k) s += P.H[tid*64+k]*P.b[k];
    P.Hb[tid] = s;
  }
  if (tid == 0) P.ll_acc[0] = 0.0;
  __syncthreads();
  mm<0,0,LDW>(W0, P.H, NN, P.A, NN, nullptr, 0);   // HA = H*A
  l2g(P.HA, W0);
}

// sequential: Riccati forward (with convergence), steady derived mats, backward cov tail
__global__ __launch_bounds__(256) void k1(KP P) {
  __shared__ __align__(16) float W0[LDW*NN], W1[LDW*NN], CH[LDC*NN];
  __shared__ float red[256], part[64];
  const int tid = threadIdx.x;
  int N0 = P.N0cap;
  float mabs = 1e-20f;
  bool conv = false;

  // ---- Phase A: forward Riccati ----
  for (int t = 0; t < P.N0cap; ++t) {
    if (t == 0) {
      g2l(W0, P.P0);                                          // pP_0 = prior_cov
    } else {
      mm<0,0,LDW>(W1, P.A, NN, W0, LDW, nullptr, 0);          // AP = A*fP
      mm<0,1,LDW>(W0, W1, LDW, P.AT, NN, P.Q, NN);            // pP = AP*A^T + Q
    }
    l2g(P.pP + (size_t)t*4096, W0);
    mm<0,0,LDW>(W1, P.H, NN, W0, LDW, nullptr, 0);            // HP = H*pP
    l2g(P.HPstash, W1);
    __threadfence_block(); __syncthreads();
    mm<0,1,LDC>(CH, W1, LDW, P.HT, NN, P.R, NN);              // S = HP*H^T + R
    chol65(CH, part);
    if (tid == 0) { float s=0.f; for (int j=0;j<64;++j) s += part[j]; P.ld_pref[t] = s; }
    tri_fwd(CH, W1); tri_bwd(CH, W1);                         // X = S^{-1}*HP
    mm<1,2,LDC>(CH, W1, LDW, P.HPstash, NN, W0, LDW);         // fP = pP - X^T*HP (into CH)
    copy65(W0, CH);                                           // W0 = fP
    l2g(P.fP + (size_t)t*4096, W0);
    float la = maxabs_l(W0, red);
    mabs = fmaxf(mabs, la);
    if (t > 0) {
      float d = maxdiff_lg(W0, P.fP + (size_t)(t-1)*4096, red);
      if (d <= 1e-6f*mabs) { N0 = t+1; conv = true; }
    }
    if (conv) break;
  }
  if (!conv) N0 = P.N0cap;

  // ---- Phase B: steady-state derived quantities ----
  mm<0,0,LDW>(W1, P.A, NN, W0, LDW, nullptr, 0);              // A*fP_ss
  mm<0,1,LDW>(W0, W1, LDW, P.AT, NN, P.Q, NN);                // pP_ss
  l2g(P.pPss, W0);
  l2g(P.pP + (size_t)N0*4096, W0);
  mm<0,0,LDW>(W1, P.H, NN, W0, LDW, nullptr, 0);              // HP
  mm<0,1,LDC>(CH, W1, LDW, P.HT, NN, P.R, NN);                // S
  chol65(CH, part);
  if (tid == 0) { float s=0.f; for (int j=0;j<64;++j) s += part[j]; P.metaF[0] = s; }
  tri_fwd(CH, W1); tri_bwd(CH, W1);                           // X
  l2g_T(P.Kss, W1);                                           // K_ss = X^T
  if (tid < 64) {
    float s = P.b[tid];
    for (int k = 0; k < 64; ++k) s -= W1[k*LDW + tid]*P.Hb[k];
    P.uss[tid] = s;                                           // u_ss = (I-KH) b
  }
  __syncthreads();
  set_id(W0); tri_fwd(CH, W0); tri_bwd(CH, W0);               // Sinv
  l2g(P.Sinvss, W0);
  mm<1,2,LDW>(W0, W1, LDW, P.HA, NN, P.A, NN);                // F_ss = A - X^T*HA
  l2g(P.Fss, W0);
  // C_ss = (pP_ss^{-1} A fP_ss)^T
  g2l(W0, P.fP + (size_t)(N0-1)*4096);
  mm<0,0,LDW>(W1, P.A, NN, W0, LDW, nullptr, 0);              // AF
  g2l65(CH, P.pPss);
  chol65(CH, part);
  tri_fwd(CH, W1); tri_bwd(CH, W1);                           // X2
  l2g(P.CsTss, W1);                                           // C^T
  l2g_T(P.Css, W1);                                           // C
  // C powers (for backward mean scan): C^2..C^32 and C^31
  g2l(W0, P.Css);
  mm<0,0,LDW>(W1, W0, LDW, W0, LDW, nullptr, 0); l2g(P.Pw2,  W1);
  mm<0,0,LDW>(W0, W1, LDW, W1, LDW, nullptr, 0); l2g(P.Pw4,  W0);
  mm<0,0,LDW>(W1, W0, LDW, W0, LDW, nullptr, 0); l2g(P.Pw8,  W1);
  mm<0,0,LDW>(W0, W1, LDW, W1, LDW, nullptr, 0); l2g(P.Pw16, W0);  // C^16 (kept in W0)
  mm<0,0,LDW>(W1, W0, LDW, W0, LDW, nullptr, 0); l2g(P.Cpow32, W1);
  mm<0,0,LDW>(W1, W0, LDW, P.Pw8, NN, nullptr, 0);            // C^24
  mm<0,0,LDW>(W0, W1, LDW, P.Pw4, NN, nullptr, 0);            // C^28
  mm<0,0,LDW>(W1, W0, LDW, P.Pw2, NN, nullptr, 0);            // C^30
  mm<0,0,LDW>(W0, W1, LDW, P.Css, NN, nullptr, 0);            // C^31
  l2g(P.Cpow31, W0);
  // F^32
  g2l(W0, P.Fss);
  mm<0,0,LDW>(W1, W0, LDW, W0, LDW, nullptr, 0);
  mm<0,0,LDW>(W0, W1, LDW, W1, LDW, nullptr, 0);
  mm<0,0,LDW>(W1, W0, LDW, W0, LDW, nullptr, 0);
  mm<0,0,LDW>(W0, W1, LDW, W1, LDW, nullptr, 0);
  mm<0,0,LDW>(W1, W0, LDW, W0, LDW, nullptr, 0);
  l2g(P.Fpow, W1);
  // ---- backward smoother-cov tail ----
  const float* fPssG = P.fP + (size_t)(N0-1)*4096;
  g2l(W0, fPssG);                                             // sP_{T-1} = fP_ss
  l2g(P.out_cov + (size_t)(P.T-1)*4096, W0);
  {
    float* cur = W0; float* oth = W1;
    int tmin = (N0 > P.T-1-N1CAP) ? N0 : (P.T-1-N1CAP);
    int tconv = tmin;
    for (int tt = P.T-2; tt >= tmin; --tt) {
      sub_lg(oth, cur, P.pPss);                               // Dd = sP - pP_ss
      mm<0,0,LDW>(cur, P.Css, NN, oth, LDW, nullptr, 0);      // E = C*Dd
      mm<0,1,LDW>(oth, cur, LDW, P.CsTss, NN, fPssG, NN);     // sP' = fP + E*C^T
      l2g(P.out_cov + (size_t)tt*4096, oth);
      float d = maxdiff_lg(oth, P.out_cov + (size_t)(tt+1)*4096, red);
      float* tmp2 = cur; cur = oth; oth = tmp2;
      if (d <= 1e-6f*mabs) { tconv = tt; break; }
    }
    l2g(P.sPss, cur);
    if (tid == 0) { P.meta[0] = N0; P.meta[1] = tconv; P.metaF[1] = mabs; }
  }
}

// parallel per-prefix-t derived quantities
__global__ __launch_bounds__(256) void k1b(KP P) {
  __shared__ __align__(16) float W0[LDW*NN], W1[LDW*NN], CH[LDC*NN];
  __shared__ float part[64];
  const int t = blockIdx.x;
  if (t >= P.meta[0]) return;
  g2l(W0, P.pP + (size_t)t*4096);
  mm<0,0,LDW>(W1, P.H, NN, W0, LDW, nullptr, 0);              // HP
  mm<0,1,LDC>(CH, W1, LDW, P.HT, NN, P.R, NN);                // S
  chol65(CH, part);
  tri_fwd(CH, W1); tri_bwd(CH, W1);                           // X
  l2g_T(P.Kp + (size_t)t*4096, W1);
  if (threadIdx.x < 64) {
    float s = P.b[threadIdx.x];
    for (int k = 0; k < 64; ++k) s -= W1[k*LDW + threadIdx.x]*P.Hb[k];
    P.u_pref[t*64 + threadIdx.x] = s;
  }
  __syncthreads();
  set_id(W0); tri_fwd(CH, W0); tri_bwd(CH, W0);               // Sinv
  l2g(P.Sinvp + (size_t)t*4096, W0);
  mm<1,2,LDW>(W0, W1, LDW, P.HA, NN, P.A, NN);                // F_t
  l2g(P.Fp + (size_t)t*4096, W0);
  // C_t
  g2l(W0, P.fP + (size_t)t*4096);
  mm<0,0,LDW>(W1, P.A, NN, W0, LDW, nullptr, 0);              // AF
  g2l65(CH, P.pP + (size_t)(t+1)*4096);
  chol65(CH, part);
  tri_fwd(CH, W1); tri_bwd(CH, W1);                           // X2
  l2g(P.CsTp + (size_t)t*4096, W1);
  l2g_T(P.Cp + (size_t)t*4096, W1);
}

// sequential backward smoothed-cov prefix
__global__ __launch_bounds__(256) void k1c(KP P) {
  __shared__ __align__(16) float W0[LDW*NN], W1[LDW*NN];
  const int N0 = P.meta[0];
  float* cur = W0; float* oth = W1;
  g2l(cur, P.sPss);
  for (int t = N0-1; t >= 0; --t) {
    sub_lg(oth, cur, P.pP + (size_t)(t+1)*4096);
    mm<0,0,LDW>(cur, P.Cp + (size_t)t*4096, NN, oth, LDW, nullptr, 0);
    mm<0,1,LDW>(oth, cur, LDW, P.CsTp + (size_t)t*4096, NN, P.fP + (size_t)t*4096, NN);
    l2g(P.out_cov + (size_t)t*4096, oth);
    float* tmp = cur; cur = oth; oth = tmp;
  }
}

// fill steady middle region of smoothed covs
__global__ __launch_bounds__(256) void k4(KP P) {
  const int t = blockIdx.x;
  if (t < P.meta[0] || t >= P.meta[1]) return;
  float* dst = P.out_cov + (size_t)t*4096;
  for (int e = threadIdx.x*4; e < 4096; e += 1024)
    *(float4*)(dst+e) = *(const float4*)(P.sPss + e);
}

// forward mean scan: local pass (steady chunks, zero init)
__global__ __launch_bounds__(256) void k2a(KP P) {
  __shared__ float xv[64], gv[64], ty[64], red[256];
  const int c = blockIdx.x;
  const int N0 = P.meta[0];
  const int PB = (N0 + LCH - 1)/LCH;
  if (c < PB) return;
  const int tid = threadIdx.x;
  if (tid < 64) xv[tid] = 0.f;
  __syncthreads();
  for (int s = 0; s < LCH; ++s) {
    int t = c*LCH + s;
    if (tid < 64) ty[tid] = P.Y[(size_t)t*64+tid] - P.c[tid];
    __syncthreads();
    matvec256(gv, P.Kss, ty, P.uss, red);
    matvec256(xv, P.Fss, xv, gv, red);
  }
  if (tid < 64) P.u_chunk[c*64+tid] = xv[tid];
}

// forward mean scan: sequential prefix + chunk carries
__global__ __launch_bounds__(256) void k2b(KP P) {
  __shared__ float xv[64], gv[64], ty[64], hp[64], red[256];
  const int tid = threadIdx.x;
  const int N0 = P.meta[0];
  const int PB = (N0 + LCH - 1)/LCH;
  const int PE = PB*LCH;
  // t = 0 (update on prior, no predict)
  if (tid < 64) xv[tid] = P.pm0[tid];
  __syncthreads();
  matvec256(hp, P.H, xv, nullptr, red);
  if (tid < 64) ty[tid] = P.Y[tid] - hp[tid] - P.c[tid];
  __syncthreads();
  matvec256(xv, P.Kp, ty, xv, red);            // fm0 = pm0 + K0*r0
  if (tid < 64) P.fm[tid] = xv[tid];
  __syncthreads();
  for (int t = 1; t < PE; ++t) {
    const float* Kt = (t < N0) ? P.Kp + (size_t)t*4096 : P.Kss;
    const float* Ft = (t < N0) ? P.Fp + (size_t)t*4096 : P.Fss;
    const float* ut = (t < N0) ? P.u_pref + t*64 : P.uss;
    if (tid < 64) ty[tid] = P.Y[(size_t)t*64+tid] - P.c[tid];
    __syncthreads();
    matvec256(gv, Kt, ty, ut, red);
    matvec256(xv, Ft, xv, gv, red);
    if (tid < 64) P.fm[(size_t)t*64+tid] = xv[tid];
    __syncthreads();
  }
  for (int c = PB; c < P.NC; ++c) {
    if (tid < 64) P.startstate[c*64+tid] = xv[tid];
    __syncthreads();
    matvec256(xv, P.Fpow, xv, P.u_chunk + c*64, red);
  }
}

// forward mean scan: replay steady chunks with true start states
__global__ __launch_bounds__(256) void k2c(KP P) {
  __shared__ float xv[64], gv[64], ty[64], red[256];
  const int c = blockIdx.x;
  const int N0 = P.meta[0];
  const int PB = (N0 + LCH - 1)/LCH;
  if (c < PB) return;
  const int tid = threadIdx.x;
  if (tid < 64) xv[tid] = P.startstate[c*64+tid];
  __syncthreads();
  for (int s = 0; s < LCH; ++s) {
    int t = c*LCH + s;
    if (tid < 64) ty[tid] = P.Y[(size_t)t*64+tid] - P.c[tid];
    __syncthreads();
    matvec256(gv, P.Kss, ty, P.uss, red);
    matvec256(xv, P.Fss, xv, gv, red);
    if (tid < 64) P.fm[(size_t)t*64+tid] = xv[tid];
    __syncthreads();
  }
}

// log-likelihood terms (one wave per t)
__global__ __launch_bounds__(64) void k5(KP P) {
  __shared__ float pmv[64], rv[64];
  const int t = blockIdx.x;
  const int N0 = P.meta[0];
  const int r = threadIdx.x;
  float pm;
  if (t == 0) {
    pm = P.pm0[r];
  } else {
    pmv[r] = P.fm[(size_t)(t-1)*64 + r];
    __syncthreads();
    float s = P.b[r];
    const float* Ar = P.A + r*64;
    for (int k = 0; k < 64; k += 4)
      s += Ar[k]*pmv[k] + Ar[k+1]*pmv[k+1] + Ar[k+2]*pmv[k+2] + Ar[k+3]*pmv[k+3];
    pm = s;
    __syncthreads();
  }
  pmv[r] = pm; __syncthreads();
  float rr = P.Y[(size_t)t*64 + r] - P.c[r];
  const float* Hr = P.H + r*64;
  for (int k = 0; k < 64; ++k) rr -= Hr[k]*pmv[k];
  rv[r] = rr; __syncthreads();
  const float* Sv = ((t < N0) ? P.Sinvp + (size_t)t*4096 : P.Sinvss) + r*64;
  float wv = 0.f;
  for (int k = 0; k < 64; ++k) wv += Sv[k]*rv[k];
  float qq = rr*wv;
  #pragma unroll
  for (int off = 32; off > 0; off >>= 1) qq += __shfl_xor(qq, off, 64);
  if (r == 0) {
    float ldt = (t < N0) ? P.ld_pref[t] : P.metaF[0];
    double llt = -58.8120661250990555 - (double)ldt - 0.5*(double)qq;
    atomicAdd(P.ll_acc, llt);
  }
}

// backward mean scan: local pass
__global__ __launch_bounds__(256) void k3a(KP P) {
  __shared__ float sv[64], wv[64], vv[64], fmv[64], red[256];
  const int c = blockIdx.x;
  const int N0 = P.meta[0];
  const int PB = (N0 + LCH - 1)/LCH;
  if (c < PB) return;
  const int tid = threadIdx.x;
  if (tid < 64) sv[tid] = 0.f;
  __syncthreads();
  int hi = (c == P.NC-1) ? P.T-2 : c*LCH + LCH - 1;
  for (int t = hi; t >= c*LCH; --t) {
    if (tid < 64) fmv[tid] = P.fm[(size_t)t*64+tid];
    __syncthreads();
    matvec256(wv, P.A, fmv, P.b, red);          // pm_{t+1} = A fm_t + b
    if (tid < 64) vv[tid] = sv[tid] - wv[tid];
    __syncthreads();
    matvec256(sv, P.Css, vv, fmv, red);         // s = fm + C*(s - pm)
  }
  if (tid < 64) P.ub_chunk[c*64+tid] = sv[tid];
}

// backward mean scan: carries + sequential prefix
__global__ __launch_bounds__(256) void k3b(KP P) {
  __shared__ float sv[64], wv[64], vv[64], fmv[64], red[256];
  const int tid = threadIdx.x;
  const int N0 = P.meta[0];
  const int PB = (N0 + LCH - 1)/LCH;
  const int PE = PB*LCH;
  if (tid < 64) {
    float v = P.fm[(size_t)(P.T-1)*64+tid];
    sv[tid] = v;
    P.out_mean[(size_t)(P.T-1)*64+tid] = v;
  }
  __syncthreads();
  for (int c = P.NC-1; c >= PB; --c) {
    if (tid < 64) P.endstate[c*64+tid] = sv[tid];
    __syncthreads();
    matvec256(sv, (c == P.NC-1) ? P.Cpow31 : P.Cpow32, sv, P.ub_chunk + c*64, red);
  }
  for (int t = PE-1; t >= 0; --t) {
    const float* Ct = (t < N0) ? P.Cp + (size_t)t*4096 : P.Css;
    if (tid < 64) fmv[tid] = P.fm[(size_t)t*64+tid];
    __syncthreads();
    matvec256(wv, P.A, fmv, P.b, red);
    if (tid < 64) vv[tid] = sv[tid] - wv[tid];
    __syncthreads();
    matvec256(sv, Ct, vv, fmv, red);
    if (tid < 64) P.out_mean[(size_t)t*64+tid] = sv[tid];
    __syncthreads();
  }
}

// backward mean scan: replay steady chunks
__global__ __launch_bounds__(256) void k3c(KP P) {
  __shared__ float sv[64], wv[64], vv[64], fmv[64], red[256];
  const int c = blockIdx.x;
  const int N0 = P.meta[0];
  const int PB = (N0 + LCH - 1)/LCH;
  if (c < PB) return;
  const int tid = threadIdx.x;
  if (tid < 64) sv[tid] = P.endstate[c*64+tid];
  __syncthreads();
  int hi = (c == P.NC-1) ? P.T-2 : c*LCH + LCH - 1;
  for (int t = hi; t >= c*LCH; --t) {
    if (tid < 64) fmv[tid] = P.fm[(size_t)t*64+tid];
    __syncthreads();
    matvec256(wv, P.A, fmv, P.b, red);
    if (tid < 64) vv[tid] = sv[tid] - wv[tid];
    __syncthreads();
    matvec256(sv, P.Css, vv, fmv, red);
    if (tid < 64) P.out_mean[(size_t)t*64+tid] = sv[tid];
    __syncthreads();
  }
}

__global__ void k6(KP P) {
  if (threadIdx.x == 0 && blockIdx.x == 0)
    P.out_ll[0] = (float)(P.ll_acc[0]);
}

// ---------- host ----------

extern "C" void kernel_launch(void* const* d_in, const int* in_sizes, int n_in,
                              void* d_out, int out_size, void* d_ws, size_t ws_size,
                              hipStream_t stream) {
  (void)n_in; (void)out_size;
  KP P;
  P.Y   = (const float*)d_in[0];
  P.A   = (const float*)d_in[1];
  P.b   = (const float*)d_in[2];
  P.Q   = (const float*)d_in[3];
  P.H   = (const float*)d_in[4];
  P.c   = (const float*)d_in[5];
  P.R   = (const float*)d_in[6];
  P.pm0 = (const float*)d_in[7];
  P.P0  = (const float*)d_in[8];
  const int T = in_sizes[0] / 64;
  const int NC = T / LCH;
  P.T = T; P.NC = NC;

  float* out = (float*)d_out;
  P.out_mean = out;
  P.out_cov  = out + (size_t)T*64;
  P.out_ll   = out + (size_t)T*64 + (size_t)T*4096;

  float* w = (float*)d_ws;
  size_t off = 0;
  auto alloc = [&](size_t n) { float* p = w + off; off += n; return p; };
  P.meta   = (int*)alloc(8);
  P.metaF  = alloc(8);
  P.ll_acc = (double*)alloc(4);
  P.fm     = alloc((size_t)T*64);
  P.AT = alloc(4096); P.HT = alloc(4096); P.HA = alloc(4096); P.Hb = alloc(64);
  P.Fss = alloc(4096); P.Kss = alloc(4096); P.Sinvss = alloc(4096);
  P.Css = alloc(4096); P.CsTss = alloc(4096); P.pPss = alloc(4096); P.sPss = alloc(4096);
  P.Fpow = alloc(4096); P.Cpow32 = alloc(4096); P.Cpow31 = alloc(4096); P.uss = alloc(64);
  P.Pw2 = alloc(4096); P.Pw4 = alloc(4096); P.Pw8 = alloc(4096); P.Pw16 = alloc(4096);
  P.u_chunk = alloc((size_t)NC*64); P.startstate = alloc((size_t)NC*64);
  P.ub_chunk = alloc((size_t)NC*64); P.endstate = alloc((size_t)NC*64);
  P.HPstash = alloc(4096);
  // prefix arrays sized by remaining workspace
  size_t fixed = off;
  size_t per_t = 7*4096 + 64 + 1;
  size_t total_f = ws_size / 4;
  long long avail = (long long)total_f - (long long)fixed - 4096 - 64;
  int cap = (avail > 0) ? (int)(avail / (long long)per_t) : 8;
  if (cap > 320) cap = 320;
  if (cap < 8) cap = 8;
  P.N0cap = cap;
  P.ld_pref = alloc(cap);
  P.u_pref  = alloc((size_t)cap*64);
  P.fP    = alloc((size_t)cap*4096);
  P.pP    = alloc((size_t)(cap+1)*4096);
  P.Kp    = alloc((size_t)cap*4096);
  P.Sinvp = alloc((size_t)cap*4096);
  P.Fp    = alloc((size_t)cap*4096);
  P.Cp    = alloc((size_t)cap*4096);
  P.CsTp  = alloc((size_t)cap*4096);

  k0<<<1, 256, 0, stream>>>(P);
  k1<<<1, 256, 0, stream>>>(P);
  k1b<<<cap, 256, 0, stream>>>(P);
  k1c<<<1, 256, 0, stream>>>(P);
  k4<<<T, 256, 0, stream>>>(P);
  k2a<<<NC, 256, 0, stream>>>(P);
  k2b<<<1, 256, 0, stream>>>(P);
  k2c<<<NC, 256, 0, stream>>>(P);
  k5<<<T, 64, 0, stream>>>(P);
  k3a<<<NC, 256, 0, stream>>>(P);
  k3b<<<1, 256, 0, stream>>>(P);
  k3c<<<NC, 256, 0, stream>>>(P);
  k6<<<1, 64, 0, stream>>>(P);
}

// Round 2
// 4546.655 us; speedup vs baseline: 1.7752x; 1.7752x over previous
//
#include <hip/hip_runtime.h>
#include <math.h>

#define NN 64
#define LDW 68      // padded LDS stride for matmul buffers (float4-aligned)
#define LDC 65      // odd stride for cholesky buffer
#define LCH 32      // mean-scan chunk length
#define N1CAP 144   // smoother-cov backward tail cap
#define N0MAX 144   // forward Riccati cap
#define CONV_EPS 1e-5f

struct KP {
  const float *Y, *A, *b, *Q, *H, *c, *R, *pm0, *P0;
  float *out_mean, *out_cov, *out_ll;
  int *meta; float *metaF; double *ll_acc;
  float *fm;
  float *AT, *HT, *HA, *Hb;
  float *Fss, *Kss, *Sinvss, *Css, *CsTss, *pPss, *sPss, *Fpow, *Cpow32, *Cpow31, *uss;
  float *Pw2, *Pw4, *Pw8, *Pw16;
  float *u_chunk, *startstate, *ub_chunk, *endstate;
  float *ld_pref, *u_pref;
  float *fP, *pP, *Kp, *Sinvp, *Fp, *Cp, *CsTp;
  int N0cap, T, NC;
};

union F4 { float4 v; float f[4]; };

// ---------- helpers (blockDim.x == 256 unless noted) ----------

__device__ __forceinline__ void g2l(float* W, const float* G) {
  for (int e = threadIdx.x*4; e < 4096; e += 1024) {
    float4 v = *(const float4*)(G + e);
    *(float4*)(W + (e>>6)*LDW + (e&63)) = v;
  }
  __syncthreads();
}
__device__ __forceinline__ void l2g(float* G, const float* W) {
  for (int e = threadIdx.x*4; e < 4096; e += 1024)
    *(float4*)(G + e) = *(const float4*)(W + (e>>6)*LDW + (e&63));
  __syncthreads();
}
__device__ __forceinline__ void l2g_T(float* G, const float* W) {
  for (int e = threadIdx.x; e < 4096; e += 256)
    G[e] = W[(e&63)*LDW + (e>>6)];
  __syncthreads();
}
__device__ __forceinline__ void g2l65(float* C, const float* G) {
  for (int e = threadIdx.x*4; e < 4096; e += 1024) {
    F4 v; v.v = *(const float4*)(G + e);
    int base = (e>>6)*LDC + (e&63);
    C[base] = v.f[0]; C[base+1] = v.f[1]; C[base+2] = v.f[2]; C[base+3] = v.f[3];
  }
  __syncthreads();
}
__device__ __forceinline__ void copyW(float* D, const float* S) {
  for (int e = threadIdx.x*4; e < 4096; e += 1024) {
    int base = (e>>6)*LDW + (e&63);
    *(float4*)(D + base) = *(const float4*)(S + base);
  }
  __syncthreads();
}
__device__ __forceinline__ void set_id(float* W) {
  for (int e = threadIdx.x; e < 4096; e += 256)
    W[(e>>6)*LDW + (e&63)] = ((e>>6) == (e&63)) ? 1.f : 0.f;
  __syncthreads();
}
__device__ __forceinline__ void sub_lg(float* D, const float* Wa, const float* G) {
  for (int e = threadIdx.x*4; e < 4096; e += 1024) {
    int base = (e>>6)*LDW + (e&63);
    F4 a, g; a.v = *(const float4*)(Wa + base); g.v = *(const float4*)(G + e);
    F4 o; o.f[0]=a.f[0]-g.f[0]; o.f[1]=a.f[1]-g.f[1]; o.f[2]=a.f[2]-g.f[2]; o.f[3]=a.f[3]-g.f[3];
    *(float4*)(D + base) = o.v;
  }
  __syncthreads();
}

// cheap 2-value max reduction: wave shuffles + 8-slot LDS, 2 barriers
__device__ __forceinline__ void redpair(float& ma, float& md, float* red) {
  #pragma unroll
  for (int off = 32; off; off >>= 1) {
    ma = fmaxf(ma, __shfl_xor(ma, off, 64));
    md = fmaxf(md, __shfl_xor(md, off, 64));
  }
  const int w = threadIdx.x >> 6;
  if ((threadIdx.x & 63) == 0) { red[w] = ma; red[4 + w] = md; }
  __syncthreads();
  ma = fmaxf(fmaxf(red[0], red[1]), fmaxf(red[2], red[3]));
  md = fmaxf(fmaxf(red[4], red[5]), fmaxf(red[6], red[7]));
  __syncthreads();
}
// copy CH(65) -> W(68) fused with maxabs + maxdiff vs global prev
__device__ __forceinline__ void fuse_copy_stats(float* W, const float* C, const float* prevG,
                                                float& ma, float& md, float* red, bool dodiff) {
  float a = 0.f, d = 0.f;
  for (int e = threadIdx.x; e < 4096; e += 256) {
    float w = C[(e>>6)*LDC + (e&63)];
    W[(e>>6)*LDW + (e&63)] = w;
    a = fmaxf(a, fabsf(w));
    if (dodiff) d = fmaxf(d, fabsf(w - prevG[e]));
  }
  redpair(a, d, red);
  ma = a; md = d;
}
// store W -> G fused with maxdiff vs prevG
__device__ __forceinline__ float l2g_maxdiff(float* G, const float* W, const float* prevG, float* red) {
  float d = 0.f;
  for (int e = threadIdx.x*4; e < 4096; e += 1024) {
    F4 v; v.v = *(const float4*)(W + (e>>6)*LDW + (e&63));
    F4 pv; pv.v = *(const float4*)(prevG + e);
    *(float4*)(G + e) = v.v;
    d = fmaxf(d, fmaxf(fmaxf(fabsf(v.f[0]-pv.f[0]), fabsf(v.f[1]-pv.f[1])),
                       fmaxf(fabsf(v.f[2]-pv.f[2]), fabsf(v.f[3]-pv.f[3]))));
  }
  float a = 0.f;
  redpair(a, d, red);
  return d;
}

// D(=LDS,stride LDD) = [ADD +/-] op(A)*B
template<int TRANSA, int MODE, int LDD>
__device__ __forceinline__ void mm(float* __restrict__ D,
    const float* __restrict__ A, int lda,
    const float* __restrict__ B, int ldb,
    const float* __restrict__ ADD, int ldadd)
{
  const int tid = threadIdx.x;
  const int i0 = (tid >> 4) << 2, j0 = (tid & 15) << 2;
  float acc[4][4] = {};
  for (int k0 = 0; k0 < NN; k0 += 4) {
    F4 av[4], bv[4];
    #pragma unroll
    for (int u = 0; u < 4; ++u) {
      bv[u].v = *(const float4*)(B + (k0+u)*ldb + j0);
      av[u].v = TRANSA ? *(const float4*)(A + (k0+u)*lda + i0)
                       : *(const float4*)(A + (i0+u)*lda + k0);
    }
    #pragma unroll
    for (int kk = 0; kk < 4; ++kk) {
      #pragma unroll
      for (int di = 0; di < 4; ++di) {
        float a = TRANSA ? av[kk].f[di] : av[di].f[kk];
        #pragma unroll
        for (int dj = 0; dj < 4; ++dj) acc[di][dj] += a * bv[kk].f[dj];
      }
    }
  }
  #pragma unroll
  for (int di = 0; di < 4; ++di) {
    if (MODE == 0 && (LDD & 3) == 0) {
      F4 o;
      #pragma unroll
      for (int dj = 0; dj < 4; ++dj) o.f[dj] = acc[di][dj];
      *(float4*)(D + (i0+di)*LDD + j0) = o.v;
    } else {
      #pragma unroll
      for (int dj = 0; dj < 4; ++dj) {
        float v = acc[di][dj];
        if (MODE == 1) v = ADD[(i0+di)*ldadd + j0+dj] + v;
        if (MODE == 2) v = ADD[(i0+di)*ldadd + j0+dj] - v;
        D[(i0+di)*LDD + j0+dj] = v;
      }
    }
  }
  __syncthreads();
}

// left-looking Cholesky in stride-65 buffer; single wave. invd[j]=1/L_jj; part[j]=log(L_jj) if WANTLOG
template<bool WANTLOG>
__device__ __forceinline__ void chol65(float* Sm, float* part, float* invd) {
  const int lane = threadIdx.x;
  if (lane < 64) {
    for (int j = 0; j < NN; ++j) {
      float acc = 0.f;
      if (lane >= j) {
        acc = Sm[lane*LDC + j];
        float a0=0.f,a1=0.f,a2=0.f,a3=0.f;
        int k = 0;
        for (; k+3 < j; k += 4) {
          a0 -= Sm[lane*LDC+k  ]*Sm[j*LDC+k  ];
          a1 -= Sm[lane*LDC+k+1]*Sm[j*LDC+k+1];
          a2 -= Sm[lane*LDC+k+2]*Sm[j*LDC+k+2];
          a3 -= Sm[lane*LDC+k+3]*Sm[j*LDC+k+3];
        }
        for (; k < j; ++k) a0 -= Sm[lane*LDC+k]*Sm[j*LDC+k];
        acc += (a0+a1)+(a2+a3);
      }
      float pv = (lane == j) ? sqrtf(fmaxf(acc, 1e-30f)) : 0.f;
      pv = __shfl(pv, j, 64);
      if (lane == j) { Sm[j*LDC+j] = pv; if (WANTLOG) part[j] = logf(pv); }
      else if (lane > j) Sm[lane*LDC+j] = acc/pv;
    }
    invd[lane] = 1.0f / Sm[lane*LDC+lane];
  }
  __syncthreads();
}

// registerized two-sided triangular solve: X <- L^-T L^-1 X (64 RHS cols, 4 lanes/col)
__device__ __forceinline__ void tri_solve2(const float* __restrict__ L,
                                           const float* __restrict__ invd,
                                           float* __restrict__ X) {
  const int col = threadIdx.x >> 2, p = threadIdx.x & 3;
  const int gbase = (threadIdx.x & 63) & ~3;
  float xr[16];
  #pragma unroll
  for (int u = 0; u < 16; ++u) xr[u] = X[(4*u+p)*LDW + col];
  // forward: L y = b
  #pragma unroll
  for (int i = 0; i < NN; ++i) {
    const int idx = i >> 2, ow = i & 3;
    float yi = xr[idx] * invd[i];
    yi = __shfl(yi, gbase + ow, 64);
    if (p == ow) xr[idx] = yi;
    else if (p > ow) xr[idx] -= L[(4*idx+p)*LDC + i] * yi;
    #pragma unroll
    for (int u = idx+1; u < 16; ++u)
      xr[u] -= L[(4*u+p)*LDC + i] * yi;
  }
  // backward: L^T z = y
  #pragma unroll
  for (int i = NN-1; i >= 0; --i) {
    const int idx = i >> 2, ow = i & 3;
    float zi = xr[idx] * invd[i];
    zi = __shfl(zi, gbase + ow, 64);
    if (p == ow) xr[idx] = zi;
    else if (p < ow) xr[idx] -= L[i*LDC + 4*idx+p] * zi;
    #pragma unroll
    for (int u = 0; u < idx; ++u)
      xr[u] -= L[i*LDC + 4*u+p] * zi;
  }
  #pragma unroll
  for (int u = 0; u < 16; ++u) X[(4*u+p)*LDW + col] = xr[u];
  __syncthreads();
}

// y(LDS 64-vec) = Mg(64x64 row-major)*x + addv (nullable). y may alias x.
__device__ __forceinline__ void matvec256(float* __restrict__ y, const float* __restrict__ Mg,
    const float* __restrict__ x, const float* __restrict__ addv, float* __restrict__ red) {
  const int r = threadIdx.x & 63, p = threadIdx.x >> 6;
  const int kb = p*16;
  float s = 0.f;
  #pragma unroll
  for (int q = 0; q < 4; ++q) {
    F4 mv; mv.v = *(const float4*)(Mg + r*NN + kb + q*4);
    s += mv.f[0]*x[kb+q*4] + mv.f[1]*x[kb+q*4+1] + mv.f[2]*x[kb+q*4+2] + mv.f[3]*x[kb+q*4+3];
  }
  red[p*64 + r] = s;
  __syncthreads();
  if (threadIdx.x < 64) {
    float t = red[r] + red[64+r] + red[128+r] + red[192+r];
    y[r] = t + (addv ? addv[r] : 0.f);
  }
  __syncthreads();
}

// ---------- kernels ----------

__global__ __launch_bounds__(256) void k0(KP P) {
  __shared__ __align__(16) float W0[LDW*NN];
  const int tid = threadIdx.x;
  for (int e = tid; e < 4096; e += 256) {
    int r = e>>6, cc = e&63;
    P.AT[e] = P.A[cc*64+r];
    P.HT[e] = P.H[cc*64+r];
  }
  if (tid < 64) {
    float s = 0.f;
    for (int k = 0; k < 64; ++k) s += P.H[tid*64+k]*P.b[k];
    P.Hb[tid] = s;
  }
  if (tid == 0) P.ll_acc[0] = 0.0;
  __syncthreads();
  mm<0,0,LDW>(W0, P.H, NN, P.A, NN, nullptr, 0);   // HA = H*A
  l2g(P.HA, W0);
}

// sequential: Riccati forward (with convergence), steady derived mats, backward cov tail
__global__ __launch_bounds__(256) void k1(KP P) {
  __shared__ __align__(16) float W0[LDW*NN], W1[LDW*NN], W2[LDW*NN], CH[LDC*NN];
  __shared__ float red[16], part[64], invd[64];
  const int tid = threadIdx.x;
  int N0 = P.N0cap;
  float mabs = 1e-20f;
  bool conv = false;

  // ---- Phase A: forward Riccati ----
  for (int t = 0; t < P.N0cap; ++t) {
    if (t == 0) {
      g2l(W0, P.P0);                                          // pP_0 = prior_cov
    } else {
      mm<0,0,LDW>(W1, P.A, NN, W0, LDW, nullptr, 0);          // AP = A*fP
      mm<0,1,LDW>(W0, W1, LDW, P.AT, NN, P.Q, NN);            // pP = AP*A^T + Q
    }
    l2g(P.pP + (size_t)t*4096, W0);
    mm<0,0,LDW>(W2, P.H, NN, W0, LDW, nullptr, 0);            // HP = H*pP
    mm<0,1,LDC>(CH, W2, LDW, P.HT, NN, P.R, NN);              // S = HP*H^T + R
    chol65<false>(CH, part, invd);
    copyW(W1, W2);                                            // keep HP in W2
    tri_solve2(CH, invd, W1);                                 // X = S^{-1}*HP
    mm<1,2,LDC>(CH, W1, LDW, W2, LDW, W0, LDW);               // fP = pP - X^T*HP
    float la, d;
    fuse_copy_stats(W0, CH, P.fP + (size_t)(t>0?t-1:0)*4096, la, d, red, t > 0);
    l2g(P.fP + (size_t)t*4096, W0);
    mabs = fmaxf(mabs, la);
    if (t > 0 && d <= CONV_EPS*mabs) { N0 = t+1; conv = true; break; }
  }
  if (!conv) N0 = P.N0cap;

  // ---- Phase B: steady-state derived quantities ----
  mm<0,0,LDW>(W1, P.A, NN, W0, LDW, nullptr, 0);              // A*fP_ss
  mm<0,1,LDW>(W0, W1, LDW, P.AT, NN, P.Q, NN);                // pP_ss
  l2g(P.pPss, W0);
  l2g(P.pP + (size_t)N0*4096, W0);
  mm<0,0,LDW>(W1, P.H, NN, W0, LDW, nullptr, 0);              // HP
  mm<0,1,LDC>(CH, W1, LDW, P.HT, NN, P.R, NN);                // S
  chol65<true>(CH, part, invd);
  if (tid == 0) { float s=0.f; for (int j=0;j<64;++j) s += part[j]; P.metaF[0] = s; }
  tri_solve2(CH, invd, W1);                                   // X
  l2g_T(P.Kss, W1);                                           // K_ss = X^T
  if (tid < 64) {
    float s = P.b[tid];
    for (int k = 0; k < 64; ++k) s -= W1[k*LDW + tid]*P.Hb[k];
    P.uss[tid] = s;                                           // u_ss = (I-KH) b
  }
  __syncthreads();
  set_id(W0); tri_solve2(CH, invd, W0);                       // Sinv
  l2g(P.Sinvss, W0);
  mm<1,2,LDW>(W0, W1, LDW, P.HA, NN, P.A, NN);                // F_ss = A - X^T*HA
  l2g(P.Fss, W0);
  // C_ss = (pP_ss^{-1} A fP_ss)^T
  g2l(W0, P.fP + (size_t)(N0-1)*4096);
  mm<0,0,LDW>(W1, P.A, NN, W0, LDW, nullptr, 0);              // AF
  g2l65(CH, P.pPss);
  chol65<false>(CH, part, invd);
  tri_solve2(CH, invd, W1);                                   // X2
  l2g(P.CsTss, W1);                                           // C^T
  l2g_T(P.Css, W1);                                           // C
  // C powers: C^2..C^32, C^31
  g2l(W0, P.Css);
  mm<0,0,LDW>(W1, W0, LDW, W0, LDW, nullptr, 0); l2g(P.Pw2,  W1);
  mm<0,0,LDW>(W0, W1, LDW, W1, LDW, nullptr, 0); l2g(P.Pw4,  W0);
  mm<0,0,LDW>(W1, W0, LDW, W0, LDW, nullptr, 0); l2g(P.Pw8,  W1);
  mm<0,0,LDW>(W0, W1, LDW, W1, LDW, nullptr, 0); l2g(P.Pw16, W0);  // C^16
  mm<0,0,LDW>(W1, W0, LDW, W0, LDW, nullptr, 0); l2g(P.Cpow32, W1);
  mm<0,0,LDW>(W1, W0, LDW, P.Pw8, NN, nullptr, 0);            // C^24
  mm<0,0,LDW>(W0, W1, LDW, P.Pw4, NN, nullptr, 0);            // C^28
  mm<0,0,LDW>(W1, W0, LDW, P.Pw2, NN, nullptr, 0);            // C^30
  mm<0,0,LDW>(W0, W1, LDW, P.Css, NN, nullptr, 0);            // C^31
  l2g(P.Cpow31, W0);
  // F^32
  g2l(W0, P.Fss);
  mm<0,0,LDW>(W1, W0, LDW, W0, LDW, nullptr, 0);
  mm<0,0,LDW>(W0, W1, LDW, W1, LDW, nullptr, 0);
  mm<0,0,LDW>(W1, W0, LDW, W0, LDW, nullptr, 0);
  mm<0,0,LDW>(W0, W1, LDW, W1, LDW, nullptr, 0);
  mm<0,0,LDW>(W1, W0, LDW, W0, LDW, nullptr, 0);
  l2g(P.Fpow, W1);
  // ---- backward smoother-cov tail ----
  const float* fPssG = P.fP + (size_t)(N0-1)*4096;
  g2l(W0, fPssG);                                             // sP_{T-1} = fP_ss
  l2g(P.out_cov + (size_t)(P.T-1)*4096, W0);
  {
    float* cur = W0; float* oth = W1;
    int tmin = (N0 > P.T-1-N1CAP) ? N0 : (P.T-1-N1CAP);
    int tconv = tmin;
    for (int tt = P.T-2; tt >= tmin; --tt) {
      sub_lg(oth, cur, P.pPss);                               // Dd = sP - pP_ss
      mm<0,0,LDW>(cur, P.Css, NN, oth, LDW, nullptr, 0);      // E = C*Dd
      mm<0,1,LDW>(oth, cur, LDW, P.CsTss, NN, fPssG, NN);     // sP' = fP + E*C^T
      float d = l2g_maxdiff(P.out_cov + (size_t)tt*4096, oth,
                            P.out_cov + (size_t)(tt+1)*4096, red);
      float* tmp2 = cur; cur = oth; oth = tmp2;
      if (d <= CONV_EPS*mabs) { tconv = tt; break; }
    }
    l2g(P.sPss, cur);
    if (tid == 0) { P.meta[0] = N0; P.meta[1] = tconv; P.metaF[1] = mabs; }
  }
}

// parallel per-prefix-t derived quantities (+ per-t logdet)
__global__ __launch_bounds__(256) void k1b(KP P) {
  __shared__ __align__(16) float W0[LDW*NN], W1[LDW*NN], CH[LDC*NN];
  __shared__ float part[64], invd[64];
  const int t = blockIdx.x;
  if (t >= P.meta[0]) return;
  g2l(W0, P.pP + (size_t)t*4096);
  mm<0,0,LDW>(W1, P.H, NN, W0, LDW, nullptr, 0);              // HP
  mm<0,1,LDC>(CH, W1, LDW, P.HT, NN, P.R, NN);                // S
  chol65<true>(CH, part, invd);
  if (threadIdx.x == 0) { float s=0.f; for (int j=0;j<64;++j) s += part[j]; P.ld_pref[t] = s; }
  tri_solve2(CH, invd, W1);                                   // X
  l2g_T(P.Kp + (size_t)t*4096, W1);
  if (threadIdx.x < 64) {
    float s = P.b[threadIdx.x];
    for (int k = 0; k < 64; ++k) s -= W1[k*LDW + threadIdx.x]*P.Hb[k];
    P.u_pref[t*64 + threadIdx.x] = s;
  }
  __syncthreads();
  set_id(W0); tri_solve2(CH, invd, W0);                       // Sinv
  l2g(P.Sinvp + (size_t)t*4096, W0);
  mm<1,2,LDW>(W0, W1, LDW, P.HA, NN, P.A, NN);                // F_t
  l2g(P.Fp + (size_t)t*4096, W0);
  // C_t
  g2l(W0, P.fP + (size_t)t*4096);
  mm<0,0,LDW>(W1, P.A, NN, W0, LDW, nullptr, 0);              // AF
  g2l65(CH, P.pP + (size_t)(t+1)*4096);
  chol65<false>(CH, part, invd);
  tri_solve2(CH, invd, W1);                                   // X2
  l2g(P.CsTp + (size_t)t*4096, W1);
  l2g_T(P.Cp + (size_t)t*4096, W1);
}

// sequential backward smoothed-cov prefix
__global__ __launch_bounds__(256) void k1c(KP P) {
  __shared__ __align__(16) float W0[LDW*NN], W1[LDW*NN];
  const int N0 = P.meta[0];
  float* cur = W0; float* oth = W1;
  g2l(cur, P.sPss);
  for (int t = N0-1; t >= 0; --t) {
    sub_lg(oth, cur, P.pP + (size_t)(t+1)*4096);
    mm<0,0,LDW>(cur, P.Cp + (size_t)t*4096, NN, oth, LDW, nullptr, 0);
    mm<0,1,LDW>(oth, cur, LDW, P.CsTp + (size_t)t*4096, NN, P.fP + (size_t)t*4096, NN);
    l2g(P.out_cov + (size_t)t*4096, oth);
    float* tmp = cur; cur = oth; oth = tmp;
  }
}

// fill steady middle region of smoothed covs
__global__ __launch_bounds__(256) void k4(KP P) {
  const int t = blockIdx.x;
  if (t < P.meta[0] || t >= P.meta[1]) return;
  float* dst = P.out_cov + (size_t)t*4096;
  for (int e = threadIdx.x*4; e < 4096; e += 1024)
    *(float4*)(dst+e) = *(const float4*)(P.sPss + e);
}

// forward mean scan: local pass (steady chunks, zero init)
__global__ __launch_bounds__(256) void k2a(KP P) {
  __shared__ float xv[64], gv[64], ty[64], red[256];
  const int c = blockIdx.x;
  const int N0 = P.meta[0];
  const int PB = (N0 + LCH - 1)/LCH;
  if (c < PB) return;
  const int tid = threadIdx.x;
  if (tid < 64) xv[tid] = 0.f;
  __syncthreads();
  for (int s = 0; s < LCH; ++s) {
    int t = c*LCH + s;
    if (tid < 64) ty[tid] = P.Y[(size_t)t*64+tid] - P.c[tid];
    __syncthreads();
    matvec256(gv, P.Kss, ty, P.uss, red);
    matvec256(xv, P.Fss, xv, gv, red);
  }
  if (tid < 64) P.u_chunk[c*64+tid] = xv[tid];
}

// forward mean scan: sequential prefix + chunk carries
__global__ __launch_bounds__(256) void k2b(KP P) {
  __shared__ float xv[64], gv[64], ty[64], hp[64], red[256];
  const int tid = threadIdx.x;
  const int N0 = P.meta[0];
  const int PB = (N0 + LCH - 1)/LCH;
  const int PE = PB*LCH;
  // t = 0 (update on prior, no predict)
  if (tid < 64) xv[tid] = P.pm0[tid];
  __syncthreads();
  matvec256(hp, P.H, xv, nullptr, red);
  if (tid < 64) ty[tid] = P.Y[tid] - hp[tid] - P.c[tid];
  __syncthreads();
  matvec256(xv, P.Kp, ty, xv, red);            // fm0 = pm0 + K0*r0
  if (tid < 64) P.fm[tid] = xv[tid];
  __syncthreads();
  for (int t = 1; t < PE; ++t) {
    const float* Kt = (t < N0) ? P.Kp + (size_t)t*4096 : P.Kss;
    const float* Ft = (t < N0) ? P.Fp + (size_t)t*4096 : P.Fss;
    const float* ut = (t < N0) ? P.u_pref + t*64 : P.uss;
    if (tid < 64) ty[tid] = P.Y[(size_t)t*64+tid] - P.c[tid];
    __syncthreads();
    matvec256(gv, Kt, ty, ut, red);
    matvec256(xv, Ft, xv, gv, red);
    if (tid < 64) P.fm[(size_t)t*64+tid] = xv[tid];
    __syncthreads();
  }
  for (int c = PB; c < P.NC; ++c) {
    if (tid < 64) P.startstate[c*64+tid] = xv[tid];
    __syncthreads();
    matvec256(xv, P.Fpow, xv, P.u_chunk + c*64, red);
  }
}

// forward mean scan: replay steady chunks with true start states
__global__ __launch_bounds__(256) void k2c(KP P) {
  __shared__ float xv[64], gv[64], ty[64], red[256];
  const int c = blockIdx.x;
  const int N0 = P.meta[0];
  const int PB = (N0 + LCH - 1)/LCH;
  if (c < PB) return;
  const int tid = threadIdx.x;
  if (tid < 64) xv[tid] = P.startstate[c*64+tid];
  __syncthreads();
  for (int s = 0; s < LCH; ++s) {
    int t = c*LCH + s;
    if (tid < 64) ty[tid] = P.Y[(size_t)t*64+tid] - P.c[tid];
    __syncthreads();
    matvec256(gv, P.Kss, ty, P.uss, red);
    matvec256(xv, P.Fss, xv, gv, red);
    if (tid < 64) P.fm[(size_t)t*64+tid] = xv[tid];
    __syncthreads();
  }
}

// log-likelihood terms (one wave per t)
__global__ __launch_bounds__(64) void k5(KP P) {
  __shared__ float pmv[64], rv[64];
  const int t = blockIdx.x;
  const int N0 = P.meta[0];
  const int r = threadIdx.x;
  float pm;
  if (t == 0) {
    pm = P.pm0[r];
  } else {
    pmv[r] = P.fm[(size_t)(t-1)*64 + r];
    __syncthreads();
    float s = P.b[r];
    const float* Ar = P.A + r*64;
    for (int k = 0; k < 64; k += 4)
      s += Ar[k]*pmv[k] + Ar[k+1]*pmv[k+1] + Ar[k+2]*pmv[k+2] + Ar[k+3]*pmv[k+3];
    pm = s;
    __syncthreads();
  }
  pmv[r] = pm; __syncthreads();
  float rr = P.Y[(size_t)t*64 + r] - P.c[r];
  const float* Hr = P.H + r*64;
  for (int k = 0; k < 64; ++k) rr -= Hr[k]*pmv[k];
  rv[r] = rr; __syncthreads();
  const float* Sv = ((t < N0) ? P.Sinvp + (size_t)t*4096 : P.Sinvss) + r*64;
  float wv = 0.f;
  for (int k = 0; k < 64; ++k) wv += Sv[k]*rv[k];
  float qq = rr*wv;
  #pragma unroll
  for (int off = 32; off > 0; off >>= 1) qq += __shfl_xor(qq, off, 64);
  if (r == 0) {
    float ldt = (t < N0) ? P.ld_pref[t] : P.metaF[0];
    double llt = -58.8120661250990555 - (double)ldt - 0.5*(double)qq;
    atomicAdd(P.ll_acc, llt);
  }
}

// backward mean scan: local pass
__global__ __launch_bounds__(256) void k3a(KP P) {
  __shared__ float sv[64], wv[64], vv[64], fmv[64], red[256];
  const int c = blockIdx.x;
  const int N0 = P.meta[0];
  const int PB = (N0 + LCH - 1)/LCH;
  if (c < PB) return;
  const int tid = threadIdx.x;
  if (tid < 64) sv[tid] = 0.f;
  __syncthreads();
  int hi = (c == P.NC-1) ? P.T-2 : c*LCH + LCH - 1;
  for (int t = hi; t >= c*LCH; --t) {
    if (tid < 64) fmv[tid] = P.fm[(size_t)t*64+tid];
    __syncthreads();
    matvec256(wv, P.A, fmv, P.b, red);          // pm_{t+1} = A fm_t + b
    if (tid < 64) vv[tid] = sv[tid] - wv[tid];
    __syncthreads();
    matvec256(sv, P.Css, vv, fmv, red);         // s = fm + C*(s - pm)
  }
  if (tid < 64) P.ub_chunk[c*64+tid] = sv[tid];
}

// backward mean scan: carries + sequential prefix
__global__ __launch_bounds__(256) void k3b(KP P) {
  __shared__ float sv[64], wv[64], vv[64], fmv[64], red[256];
  const int tid = threadIdx.x;
  const int N0 = P.meta[0];
  const int PB = (N0 + LCH - 1)/LCH;
  const int PE = PB*LCH;
  if (tid < 64) {
    float v = P.fm[(size_t)(P.T-1)*64+tid];
    sv[tid] = v;
    P.out_mean[(size_t)(P.T-1)*64+tid] = v;
  }
  __syncthreads();
  for (int c = P.NC-1; c >= PB; --c) {
    if (tid < 64) P.endstate[c*64+tid] = sv[tid];
    __syncthreads();
    matvec256(sv, (c == P.NC-1) ? P.Cpow31 : P.Cpow32, sv, P.ub_chunk + c*64, red);
  }
  for (int t = PE-1; t >= 0; --t) {
    const float* Ct = (t < N0) ? P.Cp + (size_t)t*4096 : P.Css;
    if (tid < 64) fmv[tid] = P.fm[(size_t)t*64+tid];
    __syncthreads();
    matvec256(wv, P.A, fmv, P.b, red);
    if (tid < 64) vv[tid] = sv[tid] - wv[tid];
    __syncthreads();
    matvec256(sv, Ct, vv, fmv, red);
    if (tid < 64) P.out_mean[(size_t)t*64+tid] = sv[tid];
    __syncthreads();
  }
}

// backward mean scan: replay steady chunks
__global__ __launch_bounds__(256) void k3c(KP P) {
  __shared__ float sv[64], wv[64], vv[64], fmv[64], red[256];
  const int c = blockIdx.x;
  const int N0 = P.meta[0];
  const int PB = (N0 + LCH - 1)/LCH;
  if (c < PB) return;
  const int tid = threadIdx.x;
  if (tid < 64) sv[tid] = P.endstate[c*64+tid];
  __syncthreads();
  int hi = (c == P.NC-1) ? P.T-2 : c*LCH + LCH - 1;
  for (int t = hi; t >= c*LCH; --t) {
    if (tid < 64) fmv[tid] = P.fm[(size_t)t*64+tid];
    __syncthreads();
    matvec256(wv, P.A, fmv, P.b, red);
    if (tid < 64) vv[tid] = sv[tid] - wv[tid];
    __syncthreads();
    matvec256(sv, P.Css, vv, fmv, red);
    if (tid < 64) P.out_mean[(size_t)t*64+tid] = sv[tid];
    __syncthreads();
  }
}

__global__ void k6(KP P) {
  if (threadIdx.x == 0 && blockIdx.x == 0)
    P.out_ll[0] = (float)(P.ll_acc[0]);
}

// ---------- host ----------

extern "C" void kernel_launch(void* const* d_in, const int* in_sizes, int n_in,
                              void* d_out, int out_size, void* d_ws, size_t ws_size,
                              hipStream_t stream) {
  (void)n_in; (void)out_size;
  KP P;
  P.Y   = (const float*)d_in[0];
  P.A   = (const float*)d_in[1];
  P.b   = (const float*)d_in[2];
  P.Q   = (const float*)d_in[3];
  P.H   = (const float*)d_in[4];
  P.c   = (const float*)d_in[5];
  P.R   = (const float*)d_in[6];
  P.pm0 = (const float*)d_in[7];
  P.P0  = (const float*)d_in[8];
  const int T = in_sizes[0] / 64;
  const int NC = T / LCH;
  P.T = T; P.NC = NC;

  float* out = (float*)d_out;
  P.out_mean = out;
  P.out_cov  = out + (size_t)T*64;
  P.out_ll   = out + (size_t)T*64 + (size_t)T*4096;

  float* w = (float*)d_ws;
  size_t off = 0;
  auto alloc = [&](size_t n) { float* p = w + off; off += n; return p; };
  P.meta   = (int*)alloc(8);
  P.metaF  = alloc(8);
  P.ll_acc = (double*)alloc(4);
  P.fm     = alloc((size_t)T*64);
  P.AT = alloc(4096); P.HT = alloc(4096); P.HA = alloc(4096); P.Hb = alloc(64);
  P.Fss = alloc(4096); P.Kss = alloc(4096); P.Sinvss = alloc(4096);
  P.Css = alloc(4096); P.CsTss = alloc(4096); P.pPss = alloc(4096); P.sPss = alloc(4096);
  P.Fpow = alloc(4096); P.Cpow32 = alloc(4096); P.Cpow31 = alloc(4096); P.uss = alloc(64);
  P.Pw2 = alloc(4096); P.Pw4 = alloc(4096); P.Pw8 = alloc(4096); P.Pw16 = alloc(4096);
  P.u_chunk = alloc((size_t)NC*64); P.startstate = alloc((size_t)NC*64);
  P.ub_chunk = alloc((size_t)NC*64); P.endstate = alloc((size_t)NC*64);
  // prefix arrays sized by remaining workspace
  size_t fixed = off;
  size_t per_t = 7*4096 + 64 + 1;
  size_t total_f = ws_size / 4;
  long long avail = (long long)total_f - (long long)fixed - 4096 - 64;
  int cap = (avail > 0) ? (int)(avail / (long long)per_t) : 8;
  if (cap > N0MAX) cap = N0MAX;
  if (cap < 8) cap = 8;
  P.N0cap = cap;
  P.ld_pref = alloc(cap);
  P.u_pref  = alloc((size_t)cap*64);
  P.fP    = alloc((size_t)cap*4096);
  P.pP    = alloc((size_t)(cap+1)*4096);
  P.Kp    = alloc((size_t)cap*4096);
  P.Sinvp = alloc((size_t)cap*4096);
  P.Fp    = alloc((size_t)cap*4096);
  P.Cp    = alloc((size_t)cap*4096);
  P.CsTp  = alloc((size_t)cap*4096);

  k0<<<1, 256, 0, stream>>>(P);
  k1<<<1, 256, 0, stream>>>(P);
  k1b<<<cap, 256, 0, stream>>>(P);
  k1c<<<1, 256, 0, stream>>>(P);
  k4<<<T, 256, 0, stream>>>(P);
  k2a<<<NC, 256, 0, stream>>>(P);
  k2b<<<1, 256, 0, stream>>>(P);
  k2c<<<NC, 256, 0, stream>>>(P);
  k5<<<T, 64, 0, stream>>>(P);
  k3a<<<NC, 256, 0, stream>>>(P);
  k3b<<<1, 256, 0, stream>>>(P);
  k3c<<<NC, 256, 0, stream>>>(P);
  k6<<<1, 64, 0, stream>>>(P);
}

// Round 3
// 3442.149 us; speedup vs baseline: 2.3448x; 1.3209x over previous
//
#include <hip/hip_runtime.h>
#include <math.h>

#define NN 64
#define LDW 68      // padded LDS stride (float4-aligned, balanced banks for b128)
#define LCH 32      // mean-scan chunk length
#define N1CAP 144   // smoother-cov backward tail cap
#define N0MAX 144   // forward Riccati cap
#define EPS_HARD 1e-5f
#define EPS_PLATEAU 5e-4f

struct KP {
  const float *Y, *A, *b, *Q, *H, *c, *R, *pm0, *P0;
  float *out_mean, *out_cov, *out_ll;
  int *meta; float *metaF; double *ll_acc;
  float *fm;
  float *AT, *HT, *HA, *Hb;
  float *Fss, *Kss, *Sinvss, *Css, *CsTss, *pPss, *sPss, *Fpow, *Cpow32, *Cpow31, *uss;
  float *Pw2, *Pw4, *Pw8, *Pw16;
  float *u_chunk, *startstate, *ub_chunk, *endstate;
  float *ld_pref, *u_pref;
  double *llbuf;
  float *fP, *pP, *Kp, *Sinvp, *Fp, *Cp, *CsTp;
  int N0cap, T, NC;
};

union F4 { float4 v; float f[4]; };

// ---------- helpers (blockDim.x == 256 unless noted) ----------

__device__ __forceinline__ void g2l(float* W, const float* G) {
  for (int e = threadIdx.x*4; e < 4096; e += 1024) {
    float4 v = *(const float4*)(G + e);
    *(float4*)(W + (e>>6)*LDW + (e&63)) = v;
  }
  __syncthreads();
}
__device__ __forceinline__ void l2g(float* G, const float* W) {
  for (int e = threadIdx.x*4; e < 4096; e += 1024)
    *(float4*)(G + e) = *(const float4*)(W + (e>>6)*LDW + (e&63));
  __syncthreads();
}
__device__ __forceinline__ void l2g_T(float* G, const float* W) {
  for (int e = threadIdx.x; e < 4096; e += 256)
    G[e] = W[(e&63)*LDW + (e>>6)];
  __syncthreads();
}
__device__ __forceinline__ void copyW(float* D, const float* S) {
  for (int e = threadIdx.x*4; e < 4096; e += 1024) {
    int base = (e>>6)*LDW + (e&63);
    *(float4*)(D + base) = *(const float4*)(S + base);
  }
  __syncthreads();
}
__device__ __forceinline__ void set_id(float* W) {
  for (int e = threadIdx.x; e < 4096; e += 256)
    W[(e>>6)*LDW + (e&63)] = ((e>>6) == (e&63)) ? 1.f : 0.f;
  __syncthreads();
}
__device__ __forceinline__ void sub_lg(float* D, const float* Wa, const float* G) {
  for (int e = threadIdx.x*4; e < 4096; e += 1024) {
    int base = (e>>6)*LDW + (e&63);
    F4 a, g; a.v = *(const float4*)(Wa + base); g.v = *(const float4*)(G + e);
    F4 o; o.f[0]=a.f[0]-g.f[0]; o.f[1]=a.f[1]-g.f[1]; o.f[2]=a.f[2]-g.f[2]; o.f[3]=a.f[3]-g.f[3];
    *(float4*)(D + base) = o.v;
  }
  __syncthreads();
}

// 2-value max reduction: wave shuffles + 8-slot LDS, 2 barriers
__device__ __forceinline__ void redpair(float& ma, float& md, float* red) {
  #pragma unroll
  for (int off = 32; off; off >>= 1) {
    ma = fmaxf(ma, __shfl_xor(ma, off, 64));
    md = fmaxf(md, __shfl_xor(md, off, 64));
  }
  const int w = threadIdx.x >> 6;
  if ((threadIdx.x & 63) == 0) { red[w] = ma; red[4 + w] = md; }
  __syncthreads();
  ma = fmaxf(fmaxf(red[0], red[1]), fmaxf(red[2], red[3]));
  md = fmaxf(fmaxf(red[4], red[5]), fmaxf(red[6], red[7]));
  __syncthreads();
}
// maxabs of W + maxdiff vs global prevG
__device__ __forceinline__ void statsW(const float* W, const float* prevG,
                                       float& ma, float& md, float* red, bool dodiff) {
  float a = 0.f, d = 0.f;
  for (int e = threadIdx.x*4; e < 4096; e += 1024) {
    F4 v; v.v = *(const float4*)(W + (e>>6)*LDW + (e&63));
    F4 pv;
    if (dodiff) pv.v = *(const float4*)(prevG + e);
    #pragma unroll
    for (int q = 0; q < 4; ++q) {
      a = fmaxf(a, fabsf(v.f[q]));
      if (dodiff) d = fmaxf(d, fabsf(v.f[q] - pv.f[q]));
    }
  }
  redpair(a, d, red);
  ma = a; md = d;
}
// store W -> G fused with maxdiff vs prevG
__device__ __forceinline__ float l2g_maxdiff(float* G, const float* W, const float* prevG, float* red) {
  float d = 0.f;
  for (int e = threadIdx.x*4; e < 4096; e += 1024) {
    F4 v; v.v = *(const float4*)(W + (e>>6)*LDW + (e&63));
    F4 pv; pv.v = *(const float4*)(prevG + e);
    *(float4*)(G + e) = v.v;
    d = fmaxf(d, fmaxf(fmaxf(fabsf(v.f[0]-pv.f[0]), fabsf(v.f[1]-pv.f[1])),
                       fmaxf(fabsf(v.f[2]-pv.f[2]), fabsf(v.f[3]-pv.f[3]))));
  }
  float a = 0.f;
  redpair(a, d, red);
  return d;
}

// D(=LDS,stride LDD) = [ADD +/-] op(A)*B
template<int TRANSA, int MODE, int LDD>
__device__ __forceinline__ void mm(float* __restrict__ D,
    const float* __restrict__ A, int lda,
    const float* __restrict__ B, int ldb,
    const float* __restrict__ ADD, int ldadd)
{
  const int tid = threadIdx.x;
  const int i0 = (tid >> 4) << 2, j0 = (tid & 15) << 2;
  float acc[4][4] = {};
  for (int k0 = 0; k0 < NN; k0 += 4) {
    F4 av[4], bv[4];
    #pragma unroll
    for (int u = 0; u < 4; ++u) {
      bv[u].v = *(const float4*)(B + (k0+u)*ldb + j0);
      av[u].v = TRANSA ? *(const float4*)(A + (k0+u)*lda + i0)
                       : *(const float4*)(A + (i0+u)*lda + k0);
    }
    #pragma unroll
    for (int kk = 0; kk < 4; ++kk) {
      #pragma unroll
      for (int di = 0; di < 4; ++di) {
        float a = TRANSA ? av[kk].f[di] : av[di].f[kk];
        #pragma unroll
        for (int dj = 0; dj < 4; ++dj) acc[di][dj] += a * bv[kk].f[dj];
      }
    }
  }
  #pragma unroll
  for (int di = 0; di < 4; ++di) {
    if (MODE == 0 && (LDD & 3) == 0) {
      F4 o;
      #pragma unroll
      for (int dj = 0; dj < 4; ++dj) o.f[dj] = acc[di][dj];
      *(float4*)(D + (i0+di)*LDD + j0) = o.v;
    } else {
      #pragma unroll
      for (int dj = 0; dj < 4; ++dj) {
        float v = acc[di][dj];
        if (MODE == 1) v = ADD[(i0+di)*ldadd + j0+dj] + v;
        if (MODE == 2) v = ADD[(i0+di)*ldadd + j0+dj] - v;
        D[(i0+di)*LDD + j0+dj] = v;
      }
    }
  }
  __syncthreads();
}

// panel-16 Cholesky in stride-LDW buffer (256 threads).
// Upper triangle is zeroed. invd[j]=1/L_jj; part[j]=log(L_jj) if WANTLOG.
template<bool WANTLOG>
__device__ __forceinline__ void chol68(float* __restrict__ Sm, float* part, float* invd) {
  const int tid = threadIdx.x;
  const int lane = tid & 63;
  #pragma unroll
  for (int p = 0; p < 4; ++p) {
    const int j0 = p * 16;
    if (p > 0) {
      // left-looking update of panel p by prior columns (K = j0): 256 threads
      const int i = tid & 63;
      const int jq = (tid >> 6) * 4;
      float acc[4] = {0.f, 0.f, 0.f, 0.f};
      for (int kb = 0; kb < j0; kb += 4) {
        F4 av; av.v = *(const float4*)(Sm + i*LDW + kb);
        #pragma unroll
        for (int q = 0; q < 4; ++q) {
          F4 bv; bv.v = *(const float4*)(Sm + (j0 + jq + q)*LDW + kb);
          acc[q] += av.f[0]*bv.f[0] + av.f[1]*bv.f[1] + av.f[2]*bv.f[2] + av.f[3]*bv.f[3];
        }
      }
      #pragma unroll
      for (int q = 0; q < 4; ++q)
        Sm[i*LDW + j0 + jq + q] -= acc[q];
      __syncthreads();
    }
    // factor panel p: single wave, each lane's 16-wide row slice in registers
    if (tid < 64) {
      float t[16];
      F4 tv;
      #pragma unroll
      for (int q4 = 0; q4 < 4; ++q4) {
        tv.v = *(const float4*)(Sm + lane*LDW + j0 + 4*q4);
        t[4*q4] = tv.f[0]; t[4*q4+1] = tv.f[1]; t[4*q4+2] = tv.f[2]; t[4*q4+3] = tv.f[3];
      }
      #pragma unroll
      for (int jj = 0; jj < 16; ++jj) {
        float acc = t[jj];
        #pragma unroll
        for (int kk = 0; kk < jj; ++kk)
          acc -= __shfl(t[kk], j0 + jj, 64) * t[kk];
        float piv = __shfl(acc, j0 + jj, 64);
        float sq = sqrtf(fmaxf(piv, 1e-30f));
        float inv = 1.0f / sq;
        if (lane == j0 + jj) {
          t[jj] = sq;
          invd[j0 + jj] = inv;
          if (WANTLOG) part[j0 + jj] = logf(sq);
        } else {
          t[jj] = (lane > j0 + jj) ? acc * inv : 0.f;
        }
      }
      #pragma unroll
      for (int q4 = 0; q4 < 4; ++q4) {
        tv.f[0] = t[4*q4]; tv.f[1] = t[4*q4+1]; tv.f[2] = t[4*q4+2]; tv.f[3] = t[4*q4+3];
        *(float4*)(Sm + lane*LDW + j0 + 4*q4) = tv.v;
      }
    }
    __syncthreads();
  }
}

// registerized two-sided triangular solve: X <- L^-T L^-1 X (64 RHS cols, 4 lanes/col)
__device__ __forceinline__ void tri_solve2(const float* __restrict__ L,
                                           const float* __restrict__ invd,
                                           float* __restrict__ X) {
  const int col = threadIdx.x >> 2, p = threadIdx.x & 3;
  const int gbase = (threadIdx.x & 63) & ~3;
  float xr[16];
  #pragma unroll
  for (int u = 0; u < 16; ++u) xr[u] = X[(4*u+p)*LDW + col];
  // forward: L y = b
  #pragma unroll
  for (int i = 0; i < NN; ++i) {
    const int idx = i >> 2, ow = i & 3;
    float yi = xr[idx] * invd[i];
    yi = __shfl(yi, gbase + ow, 64);
    if (p == ow) xr[idx] = yi;
    else if (p > ow) xr[idx] -= L[(4*idx+p)*LDW + i] * yi;
    #pragma unroll
    for (int u = idx+1; u < 16; ++u)
      xr[u] -= L[(4*u+p)*LDW + i] * yi;
  }
  // backward: L^T z = y
  #pragma unroll
  for (int i = NN-1; i >= 0; --i) {
    const int idx = i >> 2, ow = i & 3;
    float zi = xr[idx] * invd[i];
    zi = __shfl(zi, gbase + ow, 64);
    if (p == ow) xr[idx] = zi;
    else if (p < ow) xr[idx] -= L[i*LDW + 4*idx+p] * zi;
    #pragma unroll
    for (int u = 0; u < idx; ++u)
      xr[u] -= L[i*LDW + 4*u+p] * zi;
  }
  #pragma unroll
  for (int u = 0; u < 16; ++u) X[(4*u+p)*LDW + col] = xr[u];
  __syncthreads();
}

// y(LDS 64-vec) = Mg(64x64 row-major)*x + addv (nullable). y may alias x.
__device__ __forceinline__ void matvec256(float* __restrict__ y, const float* __restrict__ Mg,
    const float* __restrict__ x, const float* __restrict__ addv, float* __restrict__ red) {
  const int r = threadIdx.x & 63, p = threadIdx.x >> 6;
  const int kb = p*16;
  float s = 0.f;
  #pragma unroll
  for (int q = 0; q < 4; ++q) {
    F4 mv; mv.v = *(const float4*)(Mg + r*NN + kb + q*4);
    s += mv.f[0]*x[kb+q*4] + mv.f[1]*x[kb+q*4+1] + mv.f[2]*x[kb+q*4+2] + mv.f[3]*x[kb+q*4+3];
  }
  red[p*64 + r] = s;
  __syncthreads();
  if (threadIdx.x < 64) {
    float t = red[r] + red[64+r] + red[128+r] + red[192+r];
    y[r] = t + (addv ? addv[r] : 0.f);
  }
  __syncthreads();
}

// ---------- kernels ----------

__global__ __launch_bounds__(256) void k0(KP P) {
  __shared__ __align__(16) float W0[LDW*NN];
  const int tid = threadIdx.x;
  for (int e = tid; e < 4096; e += 256) {
    int r = e>>6, cc = e&63;
    P.AT[e] = P.A[cc*64+r];
    P.HT[e] = P.H[cc*64+r];
  }
  if (tid < 64) {
    float s = 0.f;
    for (int k = 0; k < 64; ++k) s += P.H[tid*64+k]*P.b[k];
    P.Hb[tid] = s;
  }
  __syncthreads();
  mm<0,0,LDW>(W0, P.H, NN, P.A, NN, nullptr, 0);   // HA = H*A
  l2g(P.HA, W0);
}

// sequential: Riccati forward (plateau convergence), steady derived mats, backward cov tail
__global__ __launch_bounds__(256) void k1(KP P) {
  __shared__ __align__(16) float W0[LDW*NN], W1[LDW*NN], W2[LDW*NN], CH[LDW*NN];
  __shared__ float red[16], part[64], invd[64];
  const int tid = threadIdx.x;
  int N0 = P.N0cap;
  float mabs = 1e-20f;
  bool conv = false;
  float dprev = 1e30f;

  // ---- Phase A: forward Riccati (fP lives in CH across iterations) ----
  for (int t = 0; t < P.N0cap; ++t) {
    if (t == 0) {
      g2l(W0, P.P0);                                          // pP_0 = prior_cov
    } else {
      mm<0,0,LDW>(W1, P.A, NN, CH, LDW, nullptr, 0);          // AP = A*fP
      mm<0,1,LDW>(W0, W1, LDW, P.AT, NN, P.Q, NN);            // pP = AP*A^T + Q
    }
    l2g(P.pP + (size_t)t*4096, W0);
    mm<0,0,LDW>(W2, P.H, NN, W0, LDW, nullptr, 0);            // HP = H*pP
    mm<0,1,LDW>(CH, W2, LDW, P.HT, NN, P.R, NN);              // S = HP*H^T + R
    chol68<false>(CH, part, invd);
    copyW(W1, W2);                                            // X := HP (W2 keeps HP)
    tri_solve2(CH, invd, W1);                                 // X = S^{-1}*HP
    mm<1,2,LDW>(CH, W1, LDW, W2, LDW, W0, LDW);               // fP = pP - X^T*HP
    float la, d;
    statsW(CH, P.fP + (size_t)(t>0?t-1:0)*4096, la, d, red, t > 0);
    l2g(P.fP + (size_t)t*4096, CH);
    mabs = fmaxf(mabs, la);
    if (t > 0) {
      if (d <= EPS_HARD*mabs ||
          (t > 6 && d < EPS_PLATEAU*mabs && d > 0.85f*dprev)) { N0 = t+1; conv = true; }
      dprev = d;
    }
    if (conv) break;
  }
  if (!conv) N0 = P.N0cap;

  // ---- Phase B: steady-state derived quantities (CH holds fP_ss) ----
  mm<0,0,LDW>(W1, P.A, NN, CH, LDW, nullptr, 0);              // A*fP_ss
  mm<0,1,LDW>(W0, W1, LDW, P.AT, NN, P.Q, NN);                // pP_ss
  l2g(P.pPss, W0);
  l2g(P.pP + (size_t)N0*4096, W0);
  mm<0,0,LDW>(W1, P.H, NN, W0, LDW, nullptr, 0);              // HP
  mm<0,1,LDW>(CH, W1, LDW, P.HT, NN, P.R, NN);                // S
  chol68<true>(CH, part, invd);
  if (tid == 0) { float s=0.f; for (int j=0;j<64;++j) s += part[j]; P.metaF[0] = s; }
  tri_solve2(CH, invd, W1);                                   // X
  l2g_T(P.Kss, W1);                                           // K_ss = X^T
  if (tid < 64) {
    float s = P.b[tid];
    for (int k = 0; k < 64; ++k) s -= W1[k*LDW + tid]*P.Hb[k];
    P.uss[tid] = s;                                           // u_ss = (I-KH) b
  }
  __syncthreads();
  set_id(W0); tri_solve2(CH, invd, W0);                       // Sinv
  l2g(P.Sinvss, W0);
  mm<1,2,LDW>(W0, W1, LDW, P.HA, NN, P.A, NN);                // F_ss = A - X^T*HA
  l2g(P.Fss, W0);
  // C_ss = (pP_ss^{-1} A fP_ss)^T
  g2l(W0, P.fP + (size_t)(N0-1)*4096);
  mm<0,0,LDW>(W1, P.A, NN, W0, LDW, nullptr, 0);              // AF
  g2l(CH, P.pPss);
  chol68<false>(CH, part, invd);
  tri_solve2(CH, invd, W1);                                   // X2
  l2g(P.CsTss, W1);                                           // C^T
  l2g_T(P.Css, W1);                                           // C
  // C powers: C^2..C^32, C^31
  g2l(W0, P.Css);
  mm<0,0,LDW>(W1, W0, LDW, W0, LDW, nullptr, 0); l2g(P.Pw2,  W1);
  mm<0,0,LDW>(W0, W1, LDW, W1, LDW, nullptr, 0); l2g(P.Pw4,  W0);
  mm<0,0,LDW>(W1, W0, LDW, W0, LDW, nullptr, 0); l2g(P.Pw8,  W1);
  mm<0,0,LDW>(W0, W1, LDW, W1, LDW, nullptr, 0); l2g(P.Pw16, W0);  // C^16
  mm<0,0,LDW>(W1, W0, LDW, W0, LDW, nullptr, 0); l2g(P.Cpow32, W1);
  mm<0,0,LDW>(W1, W0, LDW, P.Pw8, NN, nullptr, 0);            // C^24
  mm<0,0,LDW>(W0, W1, LDW, P.Pw4, NN, nullptr, 0);            // C^28
  mm<0,0,LDW>(W1, W0, LDW, P.Pw2, NN, nullptr, 0);            // C^30
  mm<0,0,LDW>(W0, W1, LDW, P.Css, NN, nullptr, 0);            // C^31
  l2g(P.Cpow31, W0);
  // F^32
  g2l(W0, P.Fss);
  mm<0,0,LDW>(W1, W0, LDW, W0, LDW, nullptr, 0);
  mm<0,0,LDW>(W0, W1, LDW, W1, LDW, nullptr, 0);
  mm<0,0,LDW>(W1, W0, LDW, W0, LDW, nullptr, 0);
  mm<0,0,LDW>(W0, W1, LDW, W1, LDW, nullptr, 0);
  mm<0,0,LDW>(W1, W0, LDW, W0, LDW, nullptr, 0);
  l2g(P.Fpow, W1);
  // ---- backward smoother-cov tail ----
  const float* fPssG = P.fP + (size_t)(N0-1)*4096;
  g2l(W0, fPssG);                                             // sP_{T-1} = fP_ss
  l2g(P.out_cov + (size_t)(P.T-1)*4096, W0);
  {
    float* cur = W0; float* oth = W1;
    int tmin = (N0 > P.T-1-N1CAP) ? N0 : (P.T-1-N1CAP);
    int tconv = tmin;
    float dtprev = 1e30f;
    for (int tt = P.T-2; tt >= tmin; --tt) {
      sub_lg(oth, cur, P.pPss);                               // Dd = sP - pP_ss
      mm<0,0,LDW>(cur, P.Css, NN, oth, LDW, nullptr, 0);      // E = C*Dd
      mm<0,1,LDW>(oth, cur, LDW, P.CsTss, NN, fPssG, NN);     // sP' = fP + E*C^T
      float d = l2g_maxdiff(P.out_cov + (size_t)tt*4096, oth,
                            P.out_cov + (size_t)(tt+1)*4096, red);
      float* tmp2 = cur; cur = oth; oth = tmp2;
      int it = P.T-2 - tt;
      if (d <= EPS_HARD*mabs ||
          (it > 6 && d < EPS_PLATEAU*mabs && d > 0.85f*dtprev)) { tconv = tt; break; }
      dtprev = d;
    }
    l2g(P.sPss, cur);
    if (tid == 0) { P.meta[0] = N0; P.meta[1] = tconv; P.metaF[1] = mabs; }
  }
}

// parallel per-prefix-t derived quantities (+ per-t logdet)
__global__ __launch_bounds__(256) void k1b(KP P) {
  __shared__ __align__(16) float W0[LDW*NN], W1[LDW*NN], CH[LDW*NN];
  __shared__ float part[64], invd[64];
  const int t = blockIdx.x;
  if (t >= P.meta[0]) return;
  g2l(W0, P.pP + (size_t)t*4096);
  mm<0,0,LDW>(W1, P.H, NN, W0, LDW, nullptr, 0);              // HP
  mm<0,1,LDW>(CH, W1, LDW, P.HT, NN, P.R, NN);                // S
  chol68<true>(CH, part, invd);
  if (threadIdx.x == 0) { float s=0.f; for (int j=0;j<64;++j) s += part[j]; P.ld_pref[t] = s; }
  tri_solve2(CH, invd, W1);                                   // X
  l2g_T(P.Kp + (size_t)t*4096, W1);
  if (threadIdx.x < 64) {
    float s = P.b[threadIdx.x];
    for (int k = 0; k < 64; ++k) s -= W1[k*LDW + threadIdx.x]*P.Hb[k];
    P.u_pref[t*64 + threadIdx.x] = s;
  }
  __syncthreads();
  set_id(W0); tri_solve2(CH, invd, W0);                       // Sinv
  l2g(P.Sinvp + (size_t)t*4096, W0);
  mm<1,2,LDW>(W0, W1, LDW, P.HA, NN, P.A, NN);                // F_t
  l2g(P.Fp + (size_t)t*4096, W0);
  // C_t
  g2l(W0, P.fP + (size_t)t*4096);
  mm<0,0,LDW>(W1, P.A, NN, W0, LDW, nullptr, 0);              // AF
  g2l(CH, P.pP + (size_t)(t+1)*4096);
  chol68<false>(CH, part, invd);
  tri_solve2(CH, invd, W1);                                   // X2
  l2g(P.CsTp + (size_t)t*4096, W1);
  l2g_T(P.Cp + (size_t)t*4096, W1);
}

// sequential backward smoothed-cov prefix
__global__ __launch_bounds__(256) void k1c(KP P) {
  __shared__ __align__(16) float W0[LDW*NN], W1[LDW*NN];
  const int N0 = P.meta[0];
  float* cur = W0; float* oth = W1;
  g2l(cur, P.sPss);
  for (int t = N0-1; t >= 0; --t) {
    sub_lg(oth, cur, P.pP + (size_t)(t+1)*4096);
    mm<0,0,LDW>(cur, P.Cp + (size_t)t*4096, NN, oth, LDW, nullptr, 0);
    mm<0,1,LDW>(oth, cur, LDW, P.CsTp + (size_t)t*4096, NN, P.fP + (size_t)t*4096, NN);
    l2g(P.out_cov + (size_t)t*4096, oth);
    float* tmp = cur; cur = oth; oth = tmp;
  }
}

// fill steady middle region of smoothed covs
__global__ __launch_bounds__(256) void k4(KP P) {
  const int t = blockIdx.x;
  if (t < P.meta[0] || t >= P.meta[1]) return;
  float* dst = P.out_cov + (size_t)t*4096;
  for (int e = threadIdx.x*4; e < 4096; e += 1024)
    *(float4*)(dst+e) = *(const float4*)(P.sPss + e);
}

// forward mean scan: local pass (steady chunks, zero init)
__global__ __launch_bounds__(256) void k2a(KP P) {
  __shared__ float xv[64], gv[64], ty[64], red[256];
  const int c = blockIdx.x;
  const int N0 = P.meta[0];
  const int PB = (N0 + LCH - 1)/LCH;
  if (c < PB) return;
  const int tid = threadIdx.x;
  if (tid < 64) xv[tid] = 0.f;
  __syncthreads();
  for (int s = 0; s < LCH; ++s) {
    int t = c*LCH + s;
    if (tid < 64) ty[tid] = P.Y[(size_t)t*64+tid] - P.c[tid];
    __syncthreads();
    matvec256(gv, P.Kss, ty, P.uss, red);
    matvec256(xv, P.Fss, xv, gv, red);
  }
  if (tid < 64) P.u_chunk[c*64+tid] = xv[tid];
}

// forward mean scan: sequential prefix + chunk carries
__global__ __launch_bounds__(256) void k2b(KP P) {
  __shared__ float xv[64], gv[64], ty[64], hp[64], red[256];
  const int tid = threadIdx.x;
  const int N0 = P.meta[0];
  const int PB = (N0 + LCH - 1)/LCH;
  const int PE = PB*LCH;
  // t = 0 (update on prior, no predict)
  if (tid < 64) xv[tid] = P.pm0[tid];
  __syncthreads();
  matvec256(hp, P.H, xv, nullptr, red);
  if (tid < 64) ty[tid] = P.Y[tid] - hp[tid] - P.c[tid];
  __syncthreads();
  matvec256(xv, P.Kp, ty, xv, red);            // fm0 = pm0 + K0*r0
  if (tid < 64) P.fm[tid] = xv[tid];
  __syncthreads();
  for (int t = 1; t < PE; ++t) {
    const float* Kt = (t < N0) ? P.Kp + (size_t)t*4096 : P.Kss;
    const float* Ft = (t < N0) ? P.Fp + (size_t)t*4096 : P.Fss;
    const float* ut = (t < N0) ? P.u_pref + t*64 : P.uss;
    if (tid < 64) ty[tid] = P.Y[(size_t)t*64+tid] - P.c[tid];
    __syncthreads();
    matvec256(gv, Kt, ty, ut, red);
    matvec256(xv, Ft, xv, gv, red);
    if (tid < 64) P.fm[(size_t)t*64+tid] = xv[tid];
    __syncthreads();
  }
  for (int c = PB; c < P.NC; ++c) {
    if (tid < 64) P.startstate[c*64+tid] = xv[tid];
    __syncthreads();
    matvec256(xv, P.Fpow, xv, P.u_chunk + c*64, red);
  }
}

// forward mean scan: replay steady chunks with true start states
__global__ __launch_bounds__(256) void k2c(KP P) {
  __shared__ float xv[64], gv[64], ty[64], red[256];
  const int c = blockIdx.x;
  const int N0 = P.meta[0];
  const int PB = (N0 + LCH - 1)/LCH;
  if (c < PB) return;
  const int tid = threadIdx.x;
  if (tid < 64) xv[tid] = P.startstate[c*64+tid];
  __syncthreads();
  for (int s = 0; s < LCH; ++s) {
    int t = c*LCH + s;
    if (tid < 64) ty[tid] = P.Y[(size_t)t*64+tid] - P.c[tid];
    __syncthreads();
    matvec256(gv, P.Kss, ty, P.uss, red);
    matvec256(xv, P.Fss, xv, gv, red);
    if (tid < 64) P.fm[(size_t)t*64+tid] = xv[tid];
    __syncthreads();
  }
}

// log-likelihood terms (one wave per t) -> llbuf
__global__ __launch_bounds__(64) void k5(KP P) {
  __shared__ float pmv[64], rv[64];
  const int t = blockIdx.x;
  const int N0 = P.meta[0];
  const int r = threadIdx.x;
  float pm;
  if (t == 0) {
    pm = P.pm0[r];
  } else {
    pmv[r] = P.fm[(size_t)(t-1)*64 + r];
    __syncthreads();
    float s = P.b[r];
    const float* Ar = P.A + r*64;
    for (int k = 0; k < 64; k += 4)
      s += Ar[k]*pmv[k] + Ar[k+1]*pmv[k+1] + Ar[k+2]*pmv[k+2] + Ar[k+3]*pmv[k+3];
    pm = s;
    __syncthreads();
  }
  pmv[r] = pm; __syncthreads();
  float rr = P.Y[(size_t)t*64 + r] - P.c[r];
  const float* Hr = P.H + r*64;
  for (int k = 0; k < 64; ++k) rr -= Hr[k]*pmv[k];
  rv[r] = rr; __syncthreads();
  const float* Sv = ((t < N0) ? P.Sinvp + (size_t)t*4096 : P.Sinvss) + r*64;
  float wv = 0.f;
  for (int k = 0; k < 64; ++k) wv += Sv[k]*rv[k];
  float qq = rr*wv;
  #pragma unroll
  for (int off = 32; off > 0; off >>= 1) qq += __shfl_xor(qq, off, 64);
  if (r == 0) {
    float ldt = (t < N0) ? P.ld_pref[t] : P.metaF[0];
    P.llbuf[t] = -58.8120661250990555 - (double)ldt - 0.5*(double)qq;
  }
}

// backward mean scan: local pass
__global__ __launch_bounds__(256) void k3a(KP P) {
  __shared__ float sv[64], wv[64], vv[64], fmv[64], red[256];
  const int c = blockIdx.x;
  const int N0 = P.meta[0];
  const int PB = (N0 + LCH - 1)/LCH;
  if (c < PB) return;
  const int tid = threadIdx.x;
  if (tid < 64) sv[tid] = 0.f;
  __syncthreads();
  int hi = (c == P.NC-1) ? P.T-2 : c*LCH + LCH - 1;
  for (int t = hi; t >= c*LCH; --t) {
    if (tid < 64) fmv[tid] = P.fm[(size_t)t*64+tid];
    __syncthreads();
    matvec256(wv, P.A, fmv, P.b, red);          // pm_{t+1} = A fm_t + b
    if (tid < 64) vv[tid] = sv[tid] - wv[tid];
    __syncthreads();
    matvec256(sv, P.Css, vv, fmv, red);         // s = fm + C*(s - pm)
  }
  if (tid < 64) P.ub_chunk[c*64+tid] = sv[tid];
}

// backward mean scan: carries + sequential prefix
__global__ __launch_bounds__(256) void k3b(KP P) {
  __shared__ float sv[64], wv[64], vv[64], fmv[64], red[256];
  const int tid = threadIdx.x;
  const int N0 = P.meta[0];
  const int PB = (N0 + LCH - 1)/LCH;
  const int PE = PB*LCH;
  if (tid < 64) {
    float v = P.fm[(size_t)(P.T-1)*64+tid];
    sv[tid] = v;
    P.out_mean[(size_t)(P.T-1)*64+tid] = v;
  }
  __syncthreads();
  for (int c = P.NC-1; c >= PB; --c) {
    if (tid < 64) P.endstate[c*64+tid] = sv[tid];
    __syncthreads();
    matvec256(sv, (c == P.NC-1) ? P.Cpow31 : P.Cpow32, sv, P.ub_chunk + c*64, red);
  }
  for (int t = PE-1; t >= 0; --t) {
    const float* Ct = (t < N0) ? P.Cp + (size_t)t*4096 : P.Css;
    if (tid < 64) fmv[tid] = P.fm[(size_t)t*64+tid];
    __syncthreads();
    matvec256(wv, P.A, fmv, P.b, red);
    if (tid < 64) vv[tid] = sv[tid] - wv[tid];
    __syncthreads();
    matvec256(sv, Ct, vv, fmv, red);
    if (tid < 64) P.out_mean[(size_t)t*64+tid] = sv[tid];
    __syncthreads();
  }
}

// backward mean scan: replay steady chunks
__global__ __launch_bounds__(256) void k3c(KP P) {
  __shared__ float sv[64], wv[64], vv[64], fmv[64], red[256];
  const int c = blockIdx.x;
  const int N0 = P.meta[0];
  const int PB = (N0 + LCH - 1)/LCH;
  if (c < PB) return;
  const int tid = threadIdx.x;
  if (tid < 64) sv[tid] = P.endstate[c*64+tid];
  __syncthreads();
  int hi = (c == P.NC-1) ? P.T-2 : c*LCH + LCH - 1;
  for (int t = hi; t >= c*LCH; --t) {
    if (tid < 64) fmv[tid] = P.fm[(size_t)t*64+tid];
    __syncthreads();
    matvec256(wv, P.A, fmv, P.b, red);
    if (tid < 64) vv[tid] = sv[tid] - wv[tid];
    __syncthreads();
    matvec256(sv, P.Css, vv, fmv, red);
    if (tid < 64) P.out_mean[(size_t)t*64+tid] = sv[tid];
    __syncthreads();
  }
}

// reduce per-t ll terms
__global__ __launch_bounds__(256) void k6(KP P) {
  __shared__ double rd[256];
  double s = 0.0;
  for (int t = threadIdx.x; t < P.T; t += 256) s += P.llbuf[t];
  rd[threadIdx.x] = s; __syncthreads();
  #pragma unroll
  for (int off = 128; off > 0; off >>= 1) {
    if ((int)threadIdx.x < off) rd[threadIdx.x] += rd[threadIdx.x + off];
    __syncthreads();
  }
  if (threadIdx.x == 0) P.out_ll[0] = (float)rd[0];
}

// ---------- host ----------

extern "C" void kernel_launch(void* const* d_in, const int* in_sizes, int n_in,
                              void* d_out, int out_size, void* d_ws, size_t ws_size,
                              hipStream_t stream) {
  (void)n_in; (void)out_size;
  KP P;
  P.Y   = (const float*)d_in[0];
  P.A   = (const float*)d_in[1];
  P.b   = (const float*)d_in[2];
  P.Q   = (const float*)d_in[3];
  P.H   = (const float*)d_in[4];
  P.c   = (const float*)d_in[5];
  P.R   = (const float*)d_in[6];
  P.pm0 = (const float*)d_in[7];
  P.P0  = (const float*)d_in[8];
  const int T = in_sizes[0] / 64;
  const int NC = T / LCH;
  P.T = T; P.NC = NC;

  float* out = (float*)d_out;
  P.out_mean = out;
  P.out_cov  = out + (size_t)T*64;
  P.out_ll   = out + (size_t)T*64 + (size_t)T*4096;

  float* w = (float*)d_ws;
  size_t off = 0;
  auto alloc = [&](size_t n) { float* p = w + off; off += n; return p; };
  P.meta   = (int*)alloc(8);
  P.metaF  = alloc(8);
  P.ll_acc = (double*)alloc(4);
  P.llbuf  = (double*)alloc((size_t)2*T);
  P.fm     = alloc((size_t)T*64);
  P.AT = alloc(4096); P.HT = alloc(4096); P.HA = alloc(4096); P.Hb = alloc(64);
  P.Fss = alloc(4096); P.Kss = alloc(4096); P.Sinvss = alloc(4096);
  P.Css = alloc(4096); P.CsTss = alloc(4096); P.pPss = alloc(4096); P.sPss = alloc(4096);
  P.Fpow = alloc(4096); P.Cpow32 = alloc(4096); P.Cpow31 = alloc(4096); P.uss = alloc(64);
  P.Pw2 = alloc(4096); P.Pw4 = alloc(4096); P.Pw8 = alloc(4096); P.Pw16 = alloc(4096);
  P.u_chunk = alloc((size_t)NC*64); P.startstate = alloc((size_t)NC*64);
  P.ub_chunk = alloc((size_t)NC*64); P.endstate = alloc((size_t)NC*64);
  // prefix arrays sized by remaining workspace
  size_t fixed = off;
  size_t per_t = 7*4096 + 64 + 1;
  size_t total_f = ws_size / 4;
  long long avail = (long long)total_f - (long long)fixed - 4096 - 64;
  int cap = (avail > 0) ? (int)(avail / (long long)per_t) : 8;
  if (cap > N0MAX) cap = N0MAX;
  if (cap < 8) cap = 8;
  P.N0cap = cap;
  P.ld_pref = alloc(cap);
  P.u_pref  = alloc((size_t)cap*64);
  P.fP    = alloc((size_t)cap*4096);
  P.pP    = alloc((size_t)(cap+1)*4096);
  P.Kp    = alloc((size_t)cap*4096);
  P.Sinvp = alloc((size_t)cap*4096);
  P.Fp    = alloc((size_t)cap*4096);
  P.Cp    = alloc((size_t)cap*4096);
  P.CsTp  = alloc((size_t)cap*4096);

  k0<<<1, 256, 0, stream>>>(P);
  k1<<<1, 256, 0, stream>>>(P);
  k1b<<<cap, 256, 0, stream>>>(P);
  k1c<<<1, 256, 0, stream>>>(P);
  k4<<<T, 256, 0, stream>>>(P);
  k2a<<<NC, 256, 0, stream>>>(P);
  k2b<<<1, 256, 0, stream>>>(P);
  k2c<<<NC, 256, 0, stream>>>(P);
  k5<<<T, 64, 0, stream>>>(P);
  k3a<<<NC, 256, 0, stream>>>(P);
  k3b<<<1, 256, 0, stream>>>(P);
  k3c<<<NC, 256, 0, stream>>>(P);
  k6<<<1, 256, 0, stream>>>(P);
}

// Round 4
// 3412.819 us; speedup vs baseline: 2.3649x; 1.0086x over previous
//
#include <hip/hip_runtime.h>
#include <math.h>

#define NN 64
#define LDW 68      // padded LDS stride (float4-aligned)
#define LCH 32      // mean-scan chunk length
#define N1CAP 144   // smoother-cov tail length (closed-form, parallel)
#define N0MAX 144   // forward Riccati cap
#define EPS_HARD 1e-5f
#define EPS_FLOOR 1.5e-3f

struct KP {
  const float *Y, *A, *b, *Q, *H, *c, *R, *pm0, *P0;
  float *out_mean, *out_cov, *out_ll;
  int *meta; float *metaF;
  float *fm;
  float *AT, *HT, *HA, *Hb;
  float *Fss, *Kss, *Sinvss, *Css, *CsTss, *pPss, *sPss, *Fpow, *Cpow32, *Cpow31, *uss;
  float *Pw2, *Pw4, *Pw8, *Pw16;
  float *u_chunk, *startstate, *ub_chunk, *endstate;
  float *ld_pref, *u_pref;
  double *llbuf;
  float *Cpows, *CpowsT, *E0g;
  float *fP, *pP, *Kp, *Sinvp, *Fp, *Cp, *CsTp;
  int N0cap, T, NC;
};

union F4 { float4 v; float f[4]; };

// ---------- helpers (blockDim.x == 256 unless noted) ----------

__device__ __forceinline__ void g2l(float* W, const float* G) {
  for (int e = threadIdx.x*4; e < 4096; e += 1024) {
    float4 v = *(const float4*)(G + e);
    *(float4*)(W + (e>>6)*LDW + (e&63)) = v;
  }
  __syncthreads();
}
__device__ __forceinline__ void l2g(float* G, const float* W) {
  for (int e = threadIdx.x*4; e < 4096; e += 1024)
    *(float4*)(G + e) = *(const float4*)(W + (e>>6)*LDW + (e&63));
  __syncthreads();
}
__device__ __forceinline__ void l2g_T(float* G, const float* W) {
  for (int e = threadIdx.x; e < 4096; e += 256)
    G[e] = W[(e&63)*LDW + (e>>6)];
  __syncthreads();
}
__device__ __forceinline__ void copyW(float* D, const float* S) {
  for (int e = threadIdx.x*4; e < 4096; e += 1024) {
    int base = (e>>6)*LDW + (e&63);
    *(float4*)(D + base) = *(const float4*)(S + base);
  }
  __syncthreads();
}
__device__ __forceinline__ void set_id(float* W) {
  for (int e = threadIdx.x; e < 4096; e += 256)
    W[(e>>6)*LDW + (e&63)] = ((e>>6) == (e&63)) ? 1.f : 0.f;
  __syncthreads();
}
__device__ __forceinline__ void sub_lg(float* D, const float* Wa, const float* G) {
  for (int e = threadIdx.x*4; e < 4096; e += 1024) {
    int base = (e>>6)*LDW + (e&63);
    F4 a, g; a.v = *(const float4*)(Wa + base); g.v = *(const float4*)(G + e);
    F4 o; o.f[0]=a.f[0]-g.f[0]; o.f[1]=a.f[1]-g.f[1]; o.f[2]=a.f[2]-g.f[2]; o.f[3]=a.f[3]-g.f[3];
    *(float4*)(D + base) = o.v;
  }
  __syncthreads();
}
// G_dst = G_src - W  (global store)
__device__ __forceinline__ void rsub_store(float* Gd, const float* Gs, const float* W) {
  for (int e = threadIdx.x*4; e < 4096; e += 1024) {
    int base = (e>>6)*LDW + (e&63);
    F4 a, g; a.v = *(const float4*)(W + base); g.v = *(const float4*)(Gs + e);
    F4 o; o.f[0]=g.f[0]-a.f[0]; o.f[1]=g.f[1]-a.f[1]; o.f[2]=g.f[2]-a.f[2]; o.f[3]=g.f[3]-a.f[3];
    *(float4*)(Gd + e) = o.v;
  }
  __syncthreads();
}

// 2-value max reduction: wave shuffles + 8-slot LDS, 2 barriers
__device__ __forceinline__ void redpair(float& ma, float& md, float* red) {
  #pragma unroll
  for (int off = 32; off; off >>= 1) {
    ma = fmaxf(ma, __shfl_xor(ma, off, 64));
    md = fmaxf(md, __shfl_xor(md, off, 64));
  }
  const int w = threadIdx.x >> 6;
  if ((threadIdx.x & 63) == 0) { red[w] = ma; red[4 + w] = md; }
  __syncthreads();
  ma = fmaxf(fmaxf(red[0], red[1]), fmaxf(red[2], red[3]));
  md = fmaxf(fmaxf(red[4], red[5]), fmaxf(red[6], red[7]));
  __syncthreads();
}
// maxabs of W + maxdiff vs global prevG
__device__ __forceinline__ void statsW(const float* W, const float* prevG,
                                       float& ma, float& md, float* red, bool dodiff) {
  float a = 0.f, d = 0.f;
  for (int e = threadIdx.x*4; e < 4096; e += 1024) {
    F4 v; v.v = *(const float4*)(W + (e>>6)*LDW + (e&63));
    F4 pv;
    if (dodiff) pv.v = *(const float4*)(prevG + e);
    #pragma unroll
    for (int q = 0; q < 4; ++q) {
      a = fmaxf(a, fabsf(v.f[q]));
      if (dodiff) d = fmaxf(d, fabsf(v.f[q] - pv.f[q]));
    }
  }
  redpair(a, d, red);
  ma = a; md = d;
}

// D(=LDS,stride LDD) = [ADD +/-] op(A)*B
template<int TRANSA, int MODE, int LDD>
__device__ __forceinline__ void mm(float* __restrict__ D,
    const float* __restrict__ A, int lda,
    const float* __restrict__ B, int ldb,
    const float* __restrict__ ADD, int ldadd)
{
  const int tid = threadIdx.x;
  const int i0 = (tid >> 4) << 2, j0 = (tid & 15) << 2;
  float acc[4][4] = {};
  for (int k0 = 0; k0 < NN; k0 += 4) {
    F4 av[4], bv[4];
    #pragma unroll
    for (int u = 0; u < 4; ++u) {
      bv[u].v = *(const float4*)(B + (k0+u)*ldb + j0);
      av[u].v = TRANSA ? *(const float4*)(A + (k0+u)*lda + i0)
                       : *(const float4*)(A + (i0+u)*lda + k0);
    }
    #pragma unroll
    for (int kk = 0; kk < 4; ++kk) {
      #pragma unroll
      for (int di = 0; di < 4; ++di) {
        float a = TRANSA ? av[kk].f[di] : av[di].f[kk];
        #pragma unroll
        for (int dj = 0; dj < 4; ++dj) acc[di][dj] += a * bv[kk].f[dj];
      }
    }
  }
  #pragma unroll
  for (int di = 0; di < 4; ++di) {
    if (MODE == 0 && (LDD & 3) == 0) {
      F4 o;
      #pragma unroll
      for (int dj = 0; dj < 4; ++dj) o.f[dj] = acc[di][dj];
      *(float4*)(D + (i0+di)*LDD + j0) = o.v;
    } else {
      #pragma unroll
      for (int dj = 0; dj < 4; ++dj) {
        float v = acc[di][dj];
        if (MODE == 1) v = ADD[(i0+di)*ldadd + j0+dj] + v;
        if (MODE == 2) v = ADD[(i0+di)*ldadd + j0+dj] - v;
        D[(i0+di)*LDD + j0+dj] = v;
      }
    }
  }
  __syncthreads();
}

// panel-16 Cholesky in stride-LDW buffer (256 threads). upper zeroed.
template<bool WANTLOG>
__device__ __forceinline__ void chol68(float* __restrict__ Sm, float* part, float* invd) {
  const int tid = threadIdx.x;
  const int lane = tid & 63;
  #pragma unroll
  for (int p = 0; p < 4; ++p) {
    const int j0 = p * 16;
    if (p > 0) {
      const int i = tid & 63;
      const int jq = (tid >> 6) * 4;
      float acc[4] = {0.f, 0.f, 0.f, 0.f};
      for (int kb = 0; kb < j0; kb += 4) {
        F4 av; av.v = *(const float4*)(Sm + i*LDW + kb);
        #pragma unroll
        for (int q = 0; q < 4; ++q) {
          F4 bv; bv.v = *(const float4*)(Sm + (j0 + jq + q)*LDW + kb);
          acc[q] += av.f[0]*bv.f[0] + av.f[1]*bv.f[1] + av.f[2]*bv.f[2] + av.f[3]*bv.f[3];
        }
      }
      #pragma unroll
      for (int q = 0; q < 4; ++q)
        Sm[i*LDW + j0 + jq + q] -= acc[q];
      __syncthreads();
    }
    if (tid < 64) {
      float t[16];
      F4 tv;
      #pragma unroll
      for (int q4 = 0; q4 < 4; ++q4) {
        tv.v = *(const float4*)(Sm + lane*LDW + j0 + 4*q4);
        t[4*q4] = tv.f[0]; t[4*q4+1] = tv.f[1]; t[4*q4+2] = tv.f[2]; t[4*q4+3] = tv.f[3];
      }
      #pragma unroll
      for (int jj = 0; jj < 16; ++jj) {
        float acc = t[jj];
        #pragma unroll
        for (int kk = 0; kk < jj; ++kk)
          acc -= __shfl(t[kk], j0 + jj, 64) * t[kk];
        float piv = __shfl(acc, j0 + jj, 64);
        float sq = sqrtf(fmaxf(piv, 1e-30f));
        float inv = 1.0f / sq;
        if (lane == j0 + jj) {
          t[jj] = sq;
          invd[j0 + jj] = inv;
          if (WANTLOG) part[j0 + jj] = logf(sq);
        } else {
          t[jj] = (lane > j0 + jj) ? acc * inv : 0.f;
        }
      }
      #pragma unroll
      for (int q4 = 0; q4 < 4; ++q4) {
        tv.f[0] = t[4*q4]; tv.f[1] = t[4*q4+1]; tv.f[2] = t[4*q4+2]; tv.f[3] = t[4*q4+3];
        *(float4*)(Sm + lane*LDW + j0 + 4*q4) = tv.v;
      }
    }
    __syncthreads();
  }
}

// registerized two-sided triangular solve: DST <- L^-T L^-1 SRC (64 RHS cols)
__device__ __forceinline__ void tri_solve2(const float* __restrict__ L,
                                           const float* __restrict__ invd,
                                           const float* __restrict__ SRC,
                                           float* __restrict__ DST) {
  const int col = threadIdx.x >> 2, p = threadIdx.x & 3;
  const int gbase = (threadIdx.x & 63) & ~3;
  float xr[16];
  #pragma unroll
  for (int u = 0; u < 16; ++u) xr[u] = SRC[(4*u+p)*LDW + col];
  #pragma unroll
  for (int i = 0; i < NN; ++i) {
    const int idx = i >> 2, ow = i & 3;
    float yi = xr[idx] * invd[i];
    yi = __shfl(yi, gbase + ow, 64);
    if (p == ow) xr[idx] = yi;
    else if (p > ow) xr[idx] -= L[(4*idx+p)*LDW + i] * yi;
    #pragma unroll
    for (int u = idx+1; u < 16; ++u)
      xr[u] -= L[(4*u+p)*LDW + i] * yi;
  }
  #pragma unroll
  for (int i = NN-1; i >= 0; --i) {
    const int idx = i >> 2, ow = i & 3;
    float zi = xr[idx] * invd[i];
    zi = __shfl(zi, gbase + ow, 64);
    if (p == ow) xr[idx] = zi;
    else if (p < ow) xr[idx] -= L[i*LDW + 4*idx+p] * zi;
    #pragma unroll
    for (int u = 0; u < idx; ++u)
      xr[u] -= L[i*LDW + 4*u+p] * zi;
  }
  #pragma unroll
  for (int u = 0; u < 16; ++u) DST[(4*u+p)*LDW + col] = xr[u];
  __syncthreads();
}

// y(LDS 64-vec) = Mg(64x64 row-major)*x + addv (nullable). y may alias x.
__device__ __forceinline__ void matvec256(float* __restrict__ y, const float* __restrict__ Mg,
    const float* __restrict__ x, const float* __restrict__ addv, float* __restrict__ red) {
  const int r = threadIdx.x & 63, p = threadIdx.x >> 6;
  const int kb = p*16;
  float s = 0.f;
  #pragma unroll
  for (int q = 0; q < 4; ++q) {
    F4 mv; mv.v = *(const float4*)(Mg + r*NN + kb + q*4);
    s += mv.f[0]*x[kb+q*4] + mv.f[1]*x[kb+q*4+1] + mv.f[2]*x[kb+q*4+2] + mv.f[3]*x[kb+q*4+3];
  }
  red[p*64 + r] = s;
  __syncthreads();
  if (threadIdx.x < 64) {
    float t = red[r] + red[64+r] + red[128+r] + red[192+r];
    y[r] = t + (addv ? addv[r] : 0.f);
  }
  __syncthreads();
}

// ---------- kernels ----------

__global__ __launch_bounds__(256) void k0(KP P) {
  __shared__ __align__(16) float W0[LDW*NN];
  const int tid = threadIdx.x;
  for (int e = tid; e < 4096; e += 256) {
    int r = e>>6, cc = e&63;
    P.AT[e] = P.A[cc*64+r];
    P.HT[e] = P.H[cc*64+r];
  }
  if (tid < 64) {
    float s = 0.f;
    for (int k = 0; k < 64; ++k) s += P.H[tid*64+k]*P.b[k];
    P.Hb[tid] = s;
  }
  __syncthreads();
  mm<0,0,LDW>(W0, P.H, NN, P.A, NN, nullptr, 0);   // HA = H*A
  l2g(P.HA, W0);
}

// sequential: Riccati forward (floor-aware convergence), steady derived mats, Stein solve
__global__ __launch_bounds__(256) void k1(KP P) {
  __shared__ __align__(16) float W0[LDW*NN], W1[LDW*NN], W2[LDW*NN], CH[LDW*NN];
  __shared__ float red[16], part[64], invd[64];
  const int tid = threadIdx.x;
  int N0 = P.N0cap;
  float mabs = 1e-20f;
  bool conv = false;
  float dprev = 1e30f;
  int nplat = 0;

  // ---- Phase A: forward Riccati (fP lives in CH across iterations) ----
  for (int t = 0; t < P.N0cap; ++t) {
    if (t == 0) {
      g2l(W0, P.P0);                                          // pP_0 = prior_cov
    } else {
      mm<0,0,LDW>(W1, P.A, NN, CH, LDW, nullptr, 0);          // AP = A*fP
      mm<0,1,LDW>(W0, W1, LDW, P.AT, NN, P.Q, NN);            // pP = AP*A^T + Q
    }
    l2g(P.pP + (size_t)t*4096, W0);
    mm<0,0,LDW>(W2, P.H, NN, W0, LDW, nullptr, 0);            // HP = H*pP
    mm<0,1,LDW>(CH, W2, LDW, P.HT, NN, P.R, NN);              // S = HP*H^T + R
    chol68<false>(CH, part, invd);
    tri_solve2(CH, invd, W2, W1);                             // X = S^{-1}*HP (W2 keeps HP)
    mm<1,2,LDW>(CH, W1, LDW, W2, LDW, W0, LDW);               // fP = pP - X^T*HP
    float la, d;
    statsW(CH, P.fP + (size_t)(t>0?t-1:0)*4096, la, d, red, t > 0);
    l2g(P.fP + (size_t)t*4096, CH);
    mabs = fmaxf(mabs, la);
    if (t > 0) {
      bool plat = (t > 8) && (d < EPS_FLOOR*mabs) && (d > 0.8f*dprev);
      nplat = plat ? nplat + 1 : 0;
      if (d <= EPS_HARD*mabs || nplat >= 2) { N0 = t+1; conv = true; }
      dprev = d;
    }
    if (conv) break;
  }
  if (!conv) N0 = P.N0cap;

  // ---- Phase B: steady-state derived quantities (CH holds fP_ss) ----
  const float* fPssG = P.fP + (size_t)(N0-1)*4096;
  mm<0,0,LDW>(W1, P.A, NN, CH, LDW, nullptr, 0);              // A*fP_ss
  mm<0,1,LDW>(W0, W1, LDW, P.AT, NN, P.Q, NN);                // pP_ss
  l2g(P.pPss, W0);
  l2g(P.pP + (size_t)N0*4096, W0);
  mm<0,0,LDW>(W1, P.H, NN, W0, LDW, nullptr, 0);              // HP
  mm<0,1,LDW>(CH, W1, LDW, P.HT, NN, P.R, NN);                // S
  chol68<true>(CH, part, invd);
  if (tid == 0) { float s=0.f; for (int j=0;j<64;++j) s += part[j]; P.metaF[0] = s; }
  tri_solve2(CH, invd, W1, W1);                               // X
  l2g_T(P.Kss, W1);                                           // K_ss = X^T
  if (tid < 64) {
    float s = P.b[tid];
    for (int k = 0; k < 64; ++k) s -= W1[k*LDW + tid]*P.Hb[k];
    P.uss[tid] = s;                                           // u_ss = (I-KH) b
  }
  __syncthreads();
  set_id(W0); tri_solve2(CH, invd, W0, W0);                   // Sinv
  l2g(P.Sinvss, W0);
  mm<1,2,LDW>(W0, W1, LDW, P.HA, NN, P.A, NN);                // F_ss = A - X^T*HA
  l2g(P.Fss, W0);
  // C_ss = (pP_ss^{-1} A fP_ss)^T
  g2l(W0, fPssG);
  mm<0,0,LDW>(W1, P.A, NN, W0, LDW, nullptr, 0);              // AF
  g2l(CH, P.pPss);
  chol68<false>(CH, part, invd);
  tri_solve2(CH, invd, W1, W1);                               // X2 = C^T
  l2g(P.CsTss, W1);
  l2g_T(P.Css, W1);
  l2g(P.CpowsT + 4096, W1);                                   // C'^1
  l2g_T(P.Cpows + 4096, W1);                                  // C^1
  // C powers for mean scan: C^2..C^32, C^31
  g2l(W0, P.Css);
  mm<0,0,LDW>(W1, W0, LDW, W0, LDW, nullptr, 0); l2g(P.Pw2,  W1);
  mm<0,0,LDW>(W0, W1, LDW, W1, LDW, nullptr, 0); l2g(P.Pw4,  W0);
  mm<0,0,LDW>(W1, W0, LDW, W0, LDW, nullptr, 0); l2g(P.Pw8,  W1);
  mm<0,0,LDW>(W0, W1, LDW, W1, LDW, nullptr, 0); l2g(P.Pw16, W0);  // C^16
  mm<0,0,LDW>(W1, W0, LDW, W0, LDW, nullptr, 0); l2g(P.Cpow32, W1);
  mm<0,0,LDW>(W1, W0, LDW, P.Pw8, NN, nullptr, 0);            // C^24
  mm<0,0,LDW>(W0, W1, LDW, P.Pw4, NN, nullptr, 0);            // C^28
  mm<0,0,LDW>(W1, W0, LDW, P.Pw2, NN, nullptr, 0);            // C^30
  mm<0,0,LDW>(W0, W1, LDW, P.Css, NN, nullptr, 0);            // C^31
  l2g(P.Cpow31, W0);
  // F^32
  g2l(W0, P.Fss);
  mm<0,0,LDW>(W1, W0, LDW, W0, LDW, nullptr, 0);
  mm<0,0,LDW>(W0, W1, LDW, W1, LDW, nullptr, 0);
  mm<0,0,LDW>(W1, W0, LDW, W0, LDW, nullptr, 0);
  mm<0,0,LDW>(W0, W1, LDW, W1, LDW, nullptr, 0);
  mm<0,0,LDW>(W1, W0, LDW, W0, LDW, nullptr, 0);
  l2g(P.Fpow, W1);
  // ---- Stein solve: sPss - C sPss C' = fPss - C pPss C' (doubling) ----
  g2l(W1, P.Css);                                             // M
  g2l(W2, P.CsTss);                                           // M'
  g2l(W0, P.pPss);
  mm<0,0,LDW>(CH, W1, LDW, W0, LDW, nullptr, 0);              // C*pPss
  mm<0,2,LDW>(W0, CH, LDW, W2, LDW, fPssG, NN);               // X = fPss - (C pPss) C'
  for (int it = 0; it < 10; ++it) {
    mm<0,0,LDW>(CH, W1, LDW, W0, LDW, nullptr, 0);            // M*X
    mm<0,1,LDW>(W0, CH, LDW, W2, LDW, W0, LDW);               // X += (M X) M'
    mm<0,0,LDW>(CH, W1, LDW, W1, LDW, nullptr, 0);            // M^2
    copyW(W1, CH);
    mm<0,0,LDW>(CH, W2, LDW, W2, LDW, nullptr, 0);            // (M')^2
    copyW(W2, CH);
  }
  l2g(P.sPss, W0);
  rsub_store(P.E0g, fPssG, W0);                               // E0 = fPss - sPss
  if (tid == 0) { P.meta[0] = N0; P.metaF[1] = mabs; }
}

// C-power ladder level: Cpows[m+j] = Cpows[m] * Cpows[j], j = 1..grid
__global__ __launch_bounds__(256) void kp(KP P, int m) {
  __shared__ __align__(16) float W0[LDW*NN];
  const int j = blockIdx.x + 1;
  mm<0,0,LDW>(W0, P.Cpows + (size_t)m*4096, NN, P.Cpows + (size_t)j*4096, NN, nullptr, 0);
  l2g(P.Cpows + (size_t)(m+j)*4096, W0);
  l2g_T(P.CpowsT + (size_t)(m+j)*4096, W0);
}

// parallel closed-form tail: sP_{T-1-k} = sPss + C^k E0 C'^k
__global__ __launch_bounds__(256) void k1d(KP P) {
  __shared__ __align__(16) float W0[LDW*NN], W2[LDW*NN];
  const int k = blockIdx.x;
  float* dst = P.out_cov + (size_t)(P.T-1-k)*4096;
  if (k == 0) {
    const float* src = P.fP + (size_t)(P.meta[0]-1)*4096;
    for (int e = threadIdx.x*4; e < 4096; e += 1024)
      *(float4*)(dst+e) = *(const float4*)(src+e);
    return;
  }
  mm<0,0,LDW>(W2, P.Cpows + (size_t)k*4096, NN, P.E0g, NN, nullptr, 0);
  mm<0,1,LDW>(W0, W2, LDW, P.CpowsT + (size_t)k*4096, NN, P.sPss, NN);
  l2g(dst, W0);
}

// parallel per-prefix-t derived quantities (+ per-t logdet)
__global__ __launch_bounds__(256) void k1b(KP P) {
  __shared__ __align__(16) float W0[LDW*NN], W1[LDW*NN], CH[LDW*NN];
  __shared__ float part[64], invd[64];
  const int t = blockIdx.x;
  if (t >= P.meta[0]) return;
  g2l(W0, P.pP + (size_t)t*4096);
  mm<0,0,LDW>(W1, P.H, NN, W0, LDW, nullptr, 0);              // HP
  mm<0,1,LDW>(CH, W1, LDW, P.HT, NN, P.R, NN);                // S
  chol68<true>(CH, part, invd);
  if (threadIdx.x == 0) { float s=0.f; for (int j=0;j<64;++j) s += part[j]; P.ld_pref[t] = s; }
  tri_solve2(CH, invd, W1, W1);                               // X
  l2g_T(P.Kp + (size_t)t*4096, W1);
  if (threadIdx.x < 64) {
    float s = P.b[threadIdx.x];
    for (int k = 0; k < 64; ++k) s -= W1[k*LDW + threadIdx.x]*P.Hb[k];
    P.u_pref[t*64 + threadIdx.x] = s;
  }
  __syncthreads();
  set_id(W0); tri_solve2(CH, invd, W0, W0);                   // Sinv
  l2g(P.Sinvp + (size_t)t*4096, W0);
  mm<1,2,LDW>(W0, W1, LDW, P.HA, NN, P.A, NN);                // F_t
  l2g(P.Fp + (size_t)t*4096, W0);
  // C_t
  g2l(W0, P.fP + (size_t)t*4096);
  mm<0,0,LDW>(W1, P.A, NN, W0, LDW, nullptr, 0);              // AF
  g2l(CH, P.pP + (size_t)(t+1)*4096);
  chol68<false>(CH, part, invd);
  tri_solve2(CH, invd, W1, W1);                               // X2
  l2g(P.CsTp + (size_t)t*4096, W1);
  l2g_T(P.Cp + (size_t)t*4096, W1);
}

// sequential backward smoothed-cov prefix
__global__ __launch_bounds__(256) void k1c(KP P) {
  __shared__ __align__(16) float W0[LDW*NN], W1[LDW*NN];
  const int N0 = P.meta[0];
  float* cur = W0; float* oth = W1;
  g2l(cur, P.sPss);
  for (int t = N0-1; t >= 0; --t) {
    sub_lg(oth, cur, P.pP + (size_t)(t+1)*4096);
    mm<0,0,LDW>(cur, P.Cp + (size_t)t*4096, NN, oth, LDW, nullptr, 0);
    mm<0,1,LDW>(oth, cur, LDW, P.CsTp + (size_t)t*4096, NN, P.fP + (size_t)t*4096, NN);
    l2g(P.out_cov + (size_t)t*4096, oth);
    float* tmp = cur; cur = oth; oth = tmp;
  }
}

// fill steady middle region of smoothed covs
__global__ __launch_bounds__(256) void k4(KP P) {
  const int t = blockIdx.x;
  if (t < P.meta[0] || t >= P.T - N1CAP) return;
  float* dst = P.out_cov + (size_t)t*4096;
  for (int e = threadIdx.x*4; e < 4096; e += 1024)
    *(float4*)(dst+e) = *(const float4*)(P.sPss + e);
}

// forward mean scan: local pass (steady chunks, zero init)
__global__ __launch_bounds__(256) void k2a(KP P) {
  __shared__ float xv[64], gv[64], ty[64], red[256];
  const int c = blockIdx.x;
  const int N0 = P.meta[0];
  const int PB = (N0 + LCH - 1)/LCH;
  if (c < PB) return;
  const int tid = threadIdx.x;
  if (tid < 64) xv[tid] = 0.f;
  __syncthreads();
  for (int s = 0; s < LCH; ++s) {
    int t = c*LCH + s;
    if (tid < 64) ty[tid] = P.Y[(size_t)t*64+tid] - P.c[tid];
    __syncthreads();
    matvec256(gv, P.Kss, ty, P.uss, red);
    matvec256(xv, P.Fss, xv, gv, red);
  }
  if (tid < 64) P.u_chunk[c*64+tid] = xv[tid];
}

// forward mean scan: sequential prefix + chunk carries
__global__ __launch_bounds__(256) void k2b(KP P) {
  __shared__ float xv[64], gv[64], ty[64], hp[64], red[256];
  const int tid = threadIdx.x;
  const int N0 = P.meta[0];
  const int PB = (N0 + LCH - 1)/LCH;
  const int PE = PB*LCH;
  if (tid < 64) xv[tid] = P.pm0[tid];
  __syncthreads();
  matvec256(hp, P.H, xv, nullptr, red);
  if (tid < 64) ty[tid] = P.Y[tid] - hp[tid] - P.c[tid];
  __syncthreads();
  matvec256(xv, P.Kp, ty, xv, red);            // fm0 = pm0 + K0*r0
  if (tid < 64) P.fm[tid] = xv[tid];
  __syncthreads();
  for (int t = 1; t < PE; ++t) {
    const float* Kt = (t < N0) ? P.Kp + (size_t)t*4096 : P.Kss;
    const float* Ft = (t < N0) ? P.Fp + (size_t)t*4096 : P.Fss;
    const float* ut = (t < N0) ? P.u_pref + t*64 : P.uss;
    if (tid < 64) ty[tid] = P.Y[(size_t)t*64+tid] - P.c[tid];
    __syncthreads();
    matvec256(gv, Kt, ty, ut, red);
    matvec256(xv, Ft, xv, gv, red);
    if (tid < 64) P.fm[(size_t)t*64+tid] = xv[tid];
    __syncthreads();
  }
  for (int c = PB; c < P.NC; ++c) {
    if (tid < 64) P.startstate[c*64+tid] = xv[tid];
    __syncthreads();
    matvec256(xv, P.Fpow, xv, P.u_chunk + c*64, red);
  }
}

// forward mean scan: replay steady chunks with true start states
__global__ __launch_bounds__(256) void k2c(KP P) {
  __shared__ float xv[64], gv[64], ty[64], red[256];
  const int c = blockIdx.x;
  const int N0 = P.meta[0];
  const int PB = (N0 + LCH - 1)/LCH;
  if (c < PB) return;
  const int tid = threadIdx.x;
  if (tid < 64) xv[tid] = P.startstate[c*64+tid];
  __syncthreads();
  for (int s = 0; s < LCH; ++s) {
    int t = c*LCH + s;
    if (tid < 64) ty[tid] = P.Y[(size_t)t*64+tid] - P.c[tid];
    __syncthreads();
    matvec256(gv, P.Kss, ty, P.uss, red);
    matvec256(xv, P.Fss, xv, gv, red);
    if (tid < 64) P.fm[(size_t)t*64+tid] = xv[tid];
    __syncthreads();
  }
}

// log-likelihood terms (one wave per t) -> llbuf
__global__ __launch_bounds__(64) void k5(KP P) {
  __shared__ float pmv[64], rv[64];
  const int t = blockIdx.x;
  const int N0 = P.meta[0];
  const int r = threadIdx.x;
  float pm;
  if (t == 0) {
    pm = P.pm0[r];
  } else {
    pmv[r] = P.fm[(size_t)(t-1)*64 + r];
    __syncthreads();
    float s = P.b[r];
    const float* Ar = P.A + r*64;
    for (int k = 0; k < 64; k += 4)
      s += Ar[k]*pmv[k] + Ar[k+1]*pmv[k+1] + Ar[k+2]*pmv[k+2] + Ar[k+3]*pmv[k+3];
    pm = s;
    __syncthreads();
  }
  pmv[r] = pm; __syncthreads();
  float rr = P.Y[(size_t)t*64 + r] - P.c[r];
  const float* Hr = P.H + r*64;
  for (int k = 0; k < 64; ++k) rr -= Hr[k]*pmv[k];
  rv[r] = rr; __syncthreads();
  const float* Sv = ((t < N0) ? P.Sinvp + (size_t)t*4096 : P.Sinvss) + r*64;
  float wv = 0.f;
  for (int k = 0; k < 64; ++k) wv += Sv[k]*rv[k];
  float qq = rr*wv;
  #pragma unroll
  for (int off = 32; off > 0; off >>= 1) qq += __shfl_xor(qq, off, 64);
  if (r == 0) {
    float ldt = (t < N0) ? P.ld_pref[t] : P.metaF[0];
    P.llbuf[t] = -58.8120661250990555 - (double)ldt - 0.5*(double)qq;
  }
}

// backward mean scan: local pass
__global__ __launch_bounds__(256) void k3a(KP P) {
  __shared__ float sv[64], wv[64], vv[64], fmv[64], red[256];
  const int c = blockIdx.x;
  const int N0 = P.meta[0];
  const int PB = (N0 + LCH - 1)/LCH;
  if (c < PB) return;
  const int tid = threadIdx.x;
  if (tid < 64) sv[tid] = 0.f;
  __syncthreads();
  int hi = (c == P.NC-1) ? P.T-2 : c*LCH + LCH - 1;
  for (int t = hi; t >= c*LCH; --t) {
    if (tid < 64) fmv[tid] = P.fm[(size_t)t*64+tid];
    __syncthreads();
    matvec256(wv, P.A, fmv, P.b, red);
    if (tid < 64) vv[tid] = sv[tid] - wv[tid];
    __syncthreads();
    matvec256(sv, P.Css, vv, fmv, red);
  }
  if (tid < 64) P.ub_chunk[c*64+tid] = sv[tid];
}

// backward mean scan: carries + sequential prefix
__global__ __launch_bounds__(256) void k3b(KP P) {
  __shared__ float sv[64], wv[64], vv[64], fmv[64], red[256];
  const int tid = threadIdx.x;
  const int N0 = P.meta[0];
  const int PB = (N0 + LCH - 1)/LCH;
  const int PE = PB*LCH;
  if (tid < 64) {
    float v = P.fm[(size_t)(P.T-1)*64+tid];
    sv[tid] = v;
    P.out_mean[(size_t)(P.T-1)*64+tid] = v;
  }
  __syncthreads();
  for (int c = P.NC-1; c >= PB; --c) {
    if (tid < 64) P.endstate[c*64+tid] = sv[tid];
    __syncthreads();
    matvec256(sv, (c == P.NC-1) ? P.Cpow31 : P.Cpow32, sv, P.ub_chunk + c*64, red);
  }
  for (int t = PE-1; t >= 0; --t) {
    const float* Ct = (t < N0) ? P.Cp + (size_t)t*4096 : P.Css;
    if (tid < 64) fmv[tid] = P.fm[(size_t)t*64+tid];
    __syncthreads();
    matvec256(wv, P.A, fmv, P.b, red);
    if (tid < 64) vv[tid] = sv[tid] - wv[tid];
    __syncthreads();
    matvec256(sv, Ct, vv, fmv, red);
    if (tid < 64) P.out_mean[(size_t)t*64+tid] = sv[tid];
    __syncthreads();
  }
}

// backward mean scan: replay steady chunks
__global__ __launch_bounds__(256) void k3c(KP P) {
  __shared__ float sv[64], wv[64], vv[64], fmv[64], red[256];
  const int c = blockIdx.x;
  const int N0 = P.meta[0];
  const int PB = (N0 + LCH - 1)/LCH;
  if (c < PB) return;
  const int tid = threadIdx.x;
  if (tid < 64) sv[tid] = P.endstate[c*64+tid];
  __syncthreads();
  int hi = (c == P.NC-1) ? P.T-2 : c*LCH + LCH - 1;
  for (int t = hi; t >= c*LCH; --t) {
    if (tid < 64) fmv[tid] = P.fm[(size_t)t*64+tid];
    __syncthreads();
    matvec256(wv, P.A, fmv, P.b, red);
    if (tid < 64) vv[tid] = sv[tid] - wv[tid];
    __syncthreads();
    matvec256(sv, P.Css, vv, fmv, red);
    if (tid < 64) P.out_mean[(size_t)t*64+tid] = sv[tid];
    __syncthreads();
  }
}

// reduce per-t ll terms
__global__ __launch_bounds__(256) void k6(KP P) {
  __shared__ double rd[256];
  double s = 0.0;
  for (int t = threadIdx.x; t < P.T; t += 256) s += P.llbuf[t];
  rd[threadIdx.x] = s; __syncthreads();
  #pragma unroll
  for (int off = 128; off > 0; off >>= 1) {
    if ((int)threadIdx.x < off) rd[threadIdx.x] += rd[threadIdx.x + off];
    __syncthreads();
  }
  if (threadIdx.x == 0) P.out_ll[0] = (float)rd[0];
}

// ---------- host ----------

extern "C" void kernel_launch(void* const* d_in, const int* in_sizes, int n_in,
                              void* d_out, int out_size, void* d_ws, size_t ws_size,
                              hipStream_t stream) {
  (void)n_in; (void)out_size;
  KP P;
  P.Y   = (const float*)d_in[0];
  P.A   = (const float*)d_in[1];
  P.b   = (const float*)d_in[2];
  P.Q   = (const float*)d_in[3];
  P.H   = (const float*)d_in[4];
  P.c   = (const float*)d_in[5];
  P.R   = (const float*)d_in[6];
  P.pm0 = (const float*)d_in[7];
  P.P0  = (const float*)d_in[8];
  const int T = in_sizes[0] / 64;
  const int NC = T / LCH;
  P.T = T; P.NC = NC;

  float* out = (float*)d_out;
  P.out_mean = out;
  P.out_cov  = out + (size_t)T*64;
  P.out_ll   = out + (size_t)T*64 + (size_t)T*4096;

  float* w = (float*)d_ws;
  size_t off = 0;
  auto alloc = [&](size_t n) { float* p = w + off; off += n; return p; };
  P.meta   = (int*)alloc(8);
  P.metaF  = alloc(8);
  P.llbuf  = (double*)alloc((size_t)2*T);
  P.fm     = alloc((size_t)T*64);
  P.AT = alloc(4096); P.HT = alloc(4096); P.HA = alloc(4096); P.Hb = alloc(64);
  P.Fss = alloc(4096); P.Kss = alloc(4096); P.Sinvss = alloc(4096);
  P.Css = alloc(4096); P.CsTss = alloc(4096); P.pPss = alloc(4096); P.sPss = alloc(4096);
  P.Fpow = alloc(4096); P.Cpow32 = alloc(4096); P.Cpow31 = alloc(4096); P.uss = alloc(64);
  P.Pw2 = alloc(4096); P.Pw4 = alloc(4096); P.Pw8 = alloc(4096); P.Pw16 = alloc(4096);
  P.u_chunk = alloc((size_t)NC*64); P.startstate = alloc((size_t)NC*64);
  P.ub_chunk = alloc((size_t)NC*64); P.endstate = alloc((size_t)NC*64);
  P.Cpows  = alloc((size_t)N1CAP*4096);
  P.CpowsT = alloc((size_t)N1CAP*4096);
  P.E0g    = alloc(4096);
  // prefix arrays sized by remaining workspace
  size_t fixed = off;
  size_t per_t = 7*4096 + 64 + 1;
  size_t total_f = ws_size / 4;
  long long avail = (long long)total_f - (long long)fixed - 4096 - 64;
  int cap = (avail > 0) ? (int)(avail / (long long)per_t) : 8;
  if (cap > N0MAX) cap = N0MAX;
  if (cap < 8) cap = 8;
  P.N0cap = cap;
  P.ld_pref = alloc(cap);
  P.u_pref  = alloc((size_t)cap*64);
  P.fP    = alloc((size_t)cap*4096);
  P.pP    = alloc((size_t)(cap+1)*4096);
  P.Kp    = alloc((size_t)cap*4096);
  P.Sinvp = alloc((size_t)cap*4096);
  P.Fp    = alloc((size_t)cap*4096);
  P.Cp    = alloc((size_t)cap*4096);
  P.CsTp  = alloc((size_t)cap*4096);

  k0<<<1, 256, 0, stream>>>(P);
  k1<<<1, 256, 0, stream>>>(P);
  // C-power ladder: after each level, powers 1..2m are available
  for (int m = 1; m < N1CAP - 1; m <<= 1) {
    int g = m < (N1CAP - 1 - m) ? m : (N1CAP - 1 - m);
    if (g > 0) kp<<<g, 256, 0, stream>>>(P, m);
  }
  k1b<<<cap, 256, 0, stream>>>(P);
  k1d<<<N1CAP, 256, 0, stream>>>(P);
  k4<<<T, 256, 0, stream>>>(P);
  k1c<<<1, 256, 0, stream>>>(P);
  k2a<<<NC, 256, 0, stream>>>(P);
  k2b<<<1, 256, 0, stream>>>(P);
  k2c<<<NC, 256, 0, stream>>>(P);
  k5<<<T, 64, 0, stream>>>(P);
  k3a<<<NC, 256, 0, stream>>>(P);
  k3b<<<1, 256, 0, stream>>>(P);
  k3c<<<NC, 256, 0, stream>>>(P);
  k6<<<1, 256, 0, stream>>>(P);
}

// Round 5
// 3083.923 us; speedup vs baseline: 2.6172x; 1.1066x over previous
//
#include <hip/hip_runtime.h>
#include <math.h>

#define NN 64
#define LDW 68      // padded LDS stride (float4-aligned)
#define LCH 32      // mean-scan chunk length
#define N1CAP 144   // smoother-cov tail length (closed-form, parallel)
#define N0MAX 144   // forward Riccati cap
#define EPS_HARD 1e-5f
#define EPS_GATE 5e-2f
#define STALL_WIN 5
#define STALL_IMP 0.75f

struct KP {
  const float *Y, *A, *b, *Q, *H, *c, *R, *pm0, *P0;
  float *out_mean, *out_cov, *out_ll;
  int *meta; float *metaF;
  float *fm;
  float *AT, *HT, *HA, *Hb;
  float *Fss, *Kss, *Sinvss, *Css, *CsTss, *pPss, *sPss, *Fpow, *Cpow32, *Cpow31, *uss;
  float *Pw2, *Pw4, *Pw8, *Pw16, *Pw64, *Pw128;
  float *u_chunk, *startstate, *ub_chunk, *endstate;
  float *ld_pref, *u_pref;
  double *llbuf;
  float *E0g;
  float *fP, *pP, *Kp, *Sinvp, *Fp, *Cp, *CsTp;
  int N0cap, T, NC;
};

union F4 { float4 v; float f[4]; };

// ---------- helpers (blockDim.x == 256 unless noted) ----------

__device__ __forceinline__ void g2l(float* W, const float* G) {
  for (int e = threadIdx.x*4; e < 4096; e += 1024) {
    float4 v = *(const float4*)(G + e);
    *(float4*)(W + (e>>6)*LDW + (e&63)) = v;
  }
  __syncthreads();
}
__device__ __forceinline__ void l2g(float* G, const float* W) {
  for (int e = threadIdx.x*4; e < 4096; e += 1024)
    *(float4*)(G + e) = *(const float4*)(W + (e>>6)*LDW + (e&63));
  __syncthreads();
}
__device__ __forceinline__ void l2g_T(float* G, const float* W) {
  for (int e = threadIdx.x; e < 4096; e += 256)
    G[e] = W[(e&63)*LDW + (e>>6)];
  __syncthreads();
}
__device__ __forceinline__ void copyW(float* D, const float* S) {
  for (int e = threadIdx.x*4; e < 4096; e += 1024) {
    int base = (e>>6)*LDW + (e&63);
    *(float4*)(D + base) = *(const float4*)(S + base);
  }
  __syncthreads();
}
__device__ __forceinline__ void set_id(float* W) {
  for (int e = threadIdx.x; e < 4096; e += 256)
    W[(e>>6)*LDW + (e&63)] = ((e>>6) == (e&63)) ? 1.f : 0.f;
  __syncthreads();
}
__device__ __forceinline__ void sub_lg(float* D, const float* Wa, const float* G) {
  for (int e = threadIdx.x*4; e < 4096; e += 1024) {
    int base = (e>>6)*LDW + (e&63);
    F4 a, g; a.v = *(const float4*)(Wa + base); g.v = *(const float4*)(G + e);
    F4 o; o.f[0]=a.f[0]-g.f[0]; o.f[1]=a.f[1]-g.f[1]; o.f[2]=a.f[2]-g.f[2]; o.f[3]=a.f[3]-g.f[3];
    *(float4*)(D + base) = o.v;
  }
  __syncthreads();
}
// G_dst = G_src - W
__device__ __forceinline__ void rsub_store(float* Gd, const float* Gs, const float* W) {
  for (int e = threadIdx.x*4; e < 4096; e += 1024) {
    int base = (e>>6)*LDW + (e&63);
    F4 a, g; a.v = *(const float4*)(W + base); g.v = *(const float4*)(Gs + e);
    F4 o; o.f[0]=g.f[0]-a.f[0]; o.f[1]=g.f[1]-a.f[1]; o.f[2]=g.f[2]-a.f[2]; o.f[3]=g.f[3]-a.f[3];
    *(float4*)(Gd + e) = o.v;
  }
  __syncthreads();
}

// 2-value max reduction
__device__ __forceinline__ void redpair(float& ma, float& md, float* red) {
  #pragma unroll
  for (int off = 32; off; off >>= 1) {
    ma = fmaxf(ma, __shfl_xor(ma, off, 64));
    md = fmaxf(md, __shfl_xor(md, off, 64));
  }
  const int w = threadIdx.x >> 6;
  if ((threadIdx.x & 63) == 0) { red[w] = ma; red[4 + w] = md; }
  __syncthreads();
  ma = fmaxf(fmaxf(red[0], red[1]), fmaxf(red[2], red[3]));
  md = fmaxf(fmaxf(red[4], red[5]), fmaxf(red[6], red[7]));
  __syncthreads();
}
// maxabs of W + maxdiff vs global prevG
__device__ __forceinline__ void statsW(const float* W, const float* prevG,
                                       float& ma, float& md, float* red, bool dodiff) {
  float a = 0.f, d = 0.f;
  for (int e = threadIdx.x*4; e < 4096; e += 1024) {
    F4 v; v.v = *(const float4*)(W + (e>>6)*LDW + (e&63));
    F4 pv;
    if (dodiff) pv.v = *(const float4*)(prevG + e);
    #pragma unroll
    for (int q = 0; q < 4; ++q) {
      a = fmaxf(a, fabsf(v.f[q]));
      if (dodiff) d = fmaxf(d, fabsf(v.f[q] - pv.f[q]));
    }
  }
  redpair(a, d, red);
  ma = a; md = d;
}

// D(=LDS,stride LDD) = [ADD +/-] op(A)*op(B)
template<int TRANSA, int TRANSB, int MODE, int LDD>
__device__ __forceinline__ void mm(float* __restrict__ D,
    const float* __restrict__ A, int lda,
    const float* __restrict__ B, int ldb,
    const float* __restrict__ ADD, int ldadd)
{
  const int tid = threadIdx.x;
  const int i0 = (tid >> 4) << 2, j0 = (tid & 15) << 2;
  float acc[4][4] = {};
  for (int k0 = 0; k0 < NN; k0 += 4) {
    F4 av[4], bv[4];
    #pragma unroll
    for (int u = 0; u < 4; ++u) {
      bv[u].v = TRANSB ? *(const float4*)(B + (j0+u)*ldb + k0)
                       : *(const float4*)(B + (k0+u)*ldb + j0);
      av[u].v = TRANSA ? *(const float4*)(A + (k0+u)*lda + i0)
                       : *(const float4*)(A + (i0+u)*lda + k0);
    }
    #pragma unroll
    for (int kk = 0; kk < 4; ++kk) {
      #pragma unroll
      for (int di = 0; di < 4; ++di) {
        float a = TRANSA ? av[kk].f[di] : av[di].f[kk];
        #pragma unroll
        for (int dj = 0; dj < 4; ++dj) {
          float bb = TRANSB ? bv[dj].f[kk] : bv[kk].f[dj];
          acc[di][dj] += a * bb;
        }
      }
    }
  }
  #pragma unroll
  for (int di = 0; di < 4; ++di) {
    if (MODE == 0 && (LDD & 3) == 0) {
      F4 o;
      #pragma unroll
      for (int dj = 0; dj < 4; ++dj) o.f[dj] = acc[di][dj];
      *(float4*)(D + (i0+di)*LDD + j0) = o.v;
    } else {
      #pragma unroll
      for (int dj = 0; dj < 4; ++dj) {
        float v = acc[di][dj];
        if (MODE == 1) v = ADD[(i0+di)*ldadd + j0+dj] + v;
        if (MODE == 2) v = ADD[(i0+di)*ldadd + j0+dj] - v;
        D[(i0+di)*LDD + j0+dj] = v;
      }
    }
  }
  __syncthreads();
}

// panel-16 Cholesky in stride-LDW buffer (256 threads). upper zeroed.
template<bool WANTLOG>
__device__ __forceinline__ void chol68(float* __restrict__ Sm, float* part, float* invd) {
  const int tid = threadIdx.x;
  const int lane = tid & 63;
  #pragma unroll
  for (int p = 0; p < 4; ++p) {
    const int j0 = p * 16;
    if (p > 0) {
      const int i = tid & 63;
      const int jq = (tid >> 6) * 4;
      float acc[4] = {0.f, 0.f, 0.f, 0.f};
      for (int kb = 0; kb < j0; kb += 4) {
        F4 av; av.v = *(const float4*)(Sm + i*LDW + kb);
        #pragma unroll
        for (int q = 0; q < 4; ++q) {
          F4 bv; bv.v = *(const float4*)(Sm + (j0 + jq + q)*LDW + kb);
          acc[q] += av.f[0]*bv.f[0] + av.f[1]*bv.f[1] + av.f[2]*bv.f[2] + av.f[3]*bv.f[3];
        }
      }
      #pragma unroll
      for (int q = 0; q < 4; ++q)
        Sm[i*LDW + j0 + jq + q] -= acc[q];
      __syncthreads();
    }
    if (tid < 64) {
      float t[16];
      F4 tv;
      #pragma unroll
      for (int q4 = 0; q4 < 4; ++q4) {
        tv.v = *(const float4*)(Sm + lane*LDW + j0 + 4*q4);
        t[4*q4] = tv.f[0]; t[4*q4+1] = tv.f[1]; t[4*q4+2] = tv.f[2]; t[4*q4+3] = tv.f[3];
      }
      #pragma unroll
      for (int jj = 0; jj < 16; ++jj) {
        float acc = t[jj];
        #pragma unroll
        for (int kk = 0; kk < jj; ++kk)
          acc -= __shfl(t[kk], j0 + jj, 64) * t[kk];
        float piv = __shfl(acc, j0 + jj, 64);
        float sq = sqrtf(fmaxf(piv, 1e-30f));
        float inv = 1.0f / sq;
        if (lane == j0 + jj) {
          t[jj] = sq;
          invd[j0 + jj] = inv;
          if (WANTLOG) part[j0 + jj] = logf(sq);
        } else {
          t[jj] = (lane > j0 + jj) ? acc * inv : 0.f;
        }
      }
      #pragma unroll
      for (int q4 = 0; q4 < 4; ++q4) {
        tv.f[0] = t[4*q4]; tv.f[1] = t[4*q4+1]; tv.f[2] = t[4*q4+2]; tv.f[3] = t[4*q4+3];
        *(float4*)(Sm + lane*LDW + j0 + 4*q4) = tv.v;
      }
    }
    __syncthreads();
  }
}

// forward-only triangular solve: DST <- L^-1 SRC (64 RHS cols, 4 lanes/col)
__device__ __forceinline__ void tri_fwd_only(const float* __restrict__ L,
                                             const float* __restrict__ invd,
                                             const float* __restrict__ SRC,
                                             float* __restrict__ DST) {
  const int col = threadIdx.x >> 2, p = threadIdx.x & 3;
  const int gbase = (threadIdx.x & 63) & ~3;
  float xr[16];
  #pragma unroll
  for (int u = 0; u < 16; ++u) xr[u] = SRC[(4*u+p)*LDW + col];
  #pragma unroll
  for (int i = 0; i < NN; ++i) {
    const int idx = i >> 2, ow = i & 3;
    float yi = xr[idx] * invd[i];
    yi = __shfl(yi, gbase + ow, 64);
    if (p == ow) xr[idx] = yi;
    else if (p > ow) xr[idx] -= L[(4*idx+p)*LDW + i] * yi;
    #pragma unroll
    for (int u = idx+1; u < 16; ++u)
      xr[u] -= L[(4*u+p)*LDW + i] * yi;
  }
  #pragma unroll
  for (int u = 0; u < 16; ++u) DST[(4*u+p)*LDW + col] = xr[u];
  __syncthreads();
}

// two-sided triangular solve: DST <- L^-T L^-1 SRC
__device__ __forceinline__ void tri_solve2(const float* __restrict__ L,
                                           const float* __restrict__ invd,
                                           const float* __restrict__ SRC,
                                           float* __restrict__ DST) {
  const int col = threadIdx.x >> 2, p = threadIdx.x & 3;
  const int gbase = (threadIdx.x & 63) & ~3;
  float xr[16];
  #pragma unroll
  for (int u = 0; u < 16; ++u) xr[u] = SRC[(4*u+p)*LDW + col];
  #pragma unroll
  for (int i = 0; i < NN; ++i) {
    const int idx = i >> 2, ow = i & 3;
    float yi = xr[idx] * invd[i];
    yi = __shfl(yi, gbase + ow, 64);
    if (p == ow) xr[idx] = yi;
    else if (p > ow) xr[idx] -= L[(4*idx+p)*LDW + i] * yi;
    #pragma unroll
    for (int u = idx+1; u < 16; ++u)
      xr[u] -= L[(4*u+p)*LDW + i] * yi;
  }
  #pragma unroll
  for (int i = NN-1; i >= 0; --i) {
    const int idx = i >> 2, ow = i & 3;
    float zi = xr[idx] * invd[i];
    zi = __shfl(zi, gbase + ow, 64);
    if (p == ow) xr[idx] = zi;
    else if (p < ow) xr[idx] -= L[i*LDW + 4*idx+p] * zi;
    #pragma unroll
    for (int u = 0; u < idx; ++u)
      xr[u] -= L[i*LDW + 4*u+p] * zi;
  }
  #pragma unroll
  for (int u = 0; u < 16; ++u) DST[(4*u+p)*LDW + col] = xr[u];
  __syncthreads();
}

// y(LDS 64-vec) = Mg(64x64 row-major)*x + addv (nullable). y may alias x.
__device__ __forceinline__ void matvec256(float* __restrict__ y, const float* __restrict__ Mg,
    const float* __restrict__ x, const float* __restrict__ addv, float* __restrict__ red) {
  const int r = threadIdx.x & 63, p = threadIdx.x >> 6;
  const int kb = p*16;
  float s = 0.f;
  #pragma unroll
  for (int q = 0; q < 4; ++q) {
    F4 mv; mv.v = *(const float4*)(Mg + r*NN + kb + q*4);
    s += mv.f[0]*x[kb+q*4] + mv.f[1]*x[kb+q*4+1] + mv.f[2]*x[kb+q*4+2] + mv.f[3]*x[kb+q*4+3];
  }
  red[p*64 + r] = s;
  __syncthreads();
  if (threadIdx.x < 64) {
    float t = red[r] + red[64+r] + red[128+r] + red[192+r];
    y[r] = t + (addv ? addv[r] : 0.f);
  }
  __syncthreads();
}

// ---------- kernels ----------

__global__ __launch_bounds__(256) void k0(KP P) {
  __shared__ __align__(16) float W0[LDW*NN];
  const int tid = threadIdx.x;
  for (int e = tid; e < 4096; e += 256) {
    int r = e>>6, cc = e&63;
    P.AT[e] = P.A[cc*64+r];
    P.HT[e] = P.H[cc*64+r];
  }
  if (tid < 64) {
    float s = 0.f;
    for (int k = 0; k < 64; ++k) s += P.H[tid*64+k]*P.b[k];
    P.Hb[tid] = s;
  }
  __syncthreads();
  mm<0,0,0,LDW>(W0, P.H, NN, P.A, NN, nullptr, 0);   // HA = H*A
  l2g(P.HA, W0);
}

// sequential: Riccati forward (stall detector), steady derived mats, Stein solve
__global__ __launch_bounds__(256) void k1(KP P) {
  __shared__ __align__(16) float W0[LDW*NN], W1[LDW*NN], W2[LDW*NN], CH[LDW*NN];
  __shared__ float red[16], part[64], invd[64];
  const int tid = threadIdx.x;
  int N0 = P.N0cap;
  float mabs = 1e-20f;
  bool conv = false;
  float dref = 1e30f;
  int tref = 0;

  // ---- Phase A: forward Riccati (fP lives in CH across iterations) ----
  for (int t = 0; t < P.N0cap; ++t) {
    if (t == 0) {
      g2l(W0, P.P0);                                          // pP_0 = prior_cov
    } else {
      mm<0,0,0,LDW>(W1, P.A, NN, CH, LDW, nullptr, 0);        // A*fP
      mm<0,0,1,LDW>(W0, W1, LDW, P.AT, NN, P.Q, NN);          // pP = (A fP) A^T + Q
    }
    l2g(P.pP + (size_t)t*4096, W0);
    mm<0,0,0,LDW>(W2, P.H, NN, W0, LDW, nullptr, 0);          // HP = H*pP
    mm<0,0,1,LDW>(CH, W2, LDW, P.HT, NN, P.R, NN);            // S = HP*H^T + R
    chol68<false>(CH, part, invd);
    tri_fwd_only(CH, invd, W2, W1);                           // U = L^{-1} HP
    mm<1,0,2,LDW>(CH, W1, LDW, W1, LDW, W0, LDW);             // fP = pP - U^T U
    float la, d;
    statsW(CH, P.fP + (size_t)(t>0?t-1:0)*4096, la, d, red, t > 0);
    l2g(P.fP + (size_t)t*4096, CH);
    mabs = fmaxf(mabs, la);
    if (t > 0) {
      if (d <= EPS_HARD*mabs) { N0 = t+1; conv = true; }
      if (d < STALL_IMP*dref) { dref = d; tref = t; }
      else if (t - tref >= STALL_WIN && t >= 12 && d < EPS_GATE*mabs) { N0 = t+1; conv = true; }
    }
    if (conv) break;
  }
  if (!conv) N0 = P.N0cap;

  // ---- Phase B: steady-state derived quantities (CH holds fP_ss) ----
  const float* fPssG = P.fP + (size_t)(N0-1)*4096;
  mm<0,0,0,LDW>(W1, P.A, NN, CH, LDW, nullptr, 0);            // A*fP_ss
  mm<0,0,1,LDW>(W0, W1, LDW, P.AT, NN, P.Q, NN);              // pP_ss
  l2g(P.pPss, W0);
  l2g(P.pP + (size_t)N0*4096, W0);
  mm<0,0,0,LDW>(W1, P.H, NN, W0, LDW, nullptr, 0);            // HP
  mm<0,0,1,LDW>(CH, W1, LDW, P.HT, NN, P.R, NN);              // S
  chol68<true>(CH, part, invd);
  if (tid == 0) { float s=0.f; for (int j=0;j<64;++j) s += part[j]; P.metaF[0] = s; }
  tri_solve2(CH, invd, W1, W1);                               // X
  l2g_T(P.Kss, W1);                                           // K_ss = X^T
  if (tid < 64) {
    float s = P.b[tid];
    for (int k = 0; k < 64; ++k) s -= W1[k*LDW + tid]*P.Hb[k];
    P.uss[tid] = s;                                           // u_ss = (I-KH) b
  }
  __syncthreads();
  set_id(W0); tri_solve2(CH, invd, W0, W0);                   // Sinv
  l2g(P.Sinvss, W0);
  mm<1,0,2,LDW>(W0, W1, LDW, P.HA, NN, P.A, NN);              // F_ss = A - X^T*HA
  l2g(P.Fss, W0);
  // C_ss = (pP_ss^{-1} A fP_ss)^T
  g2l(W0, fPssG);
  mm<0,0,0,LDW>(W1, P.A, NN, W0, LDW, nullptr, 0);            // AF
  g2l(CH, P.pPss);
  chol68<false>(CH, part, invd);
  tri_solve2(CH, invd, W1, W1);                               // X2 = C^T
  l2g(P.CsTss, W1);
  l2g_T(P.Css, W1);
  // C powers: C^2..C^32, C^31, C^64, C^128
  g2l(W0, P.Css);
  mm<0,0,0,LDW>(W1, W0, LDW, W0, LDW, nullptr, 0); l2g(P.Pw2,  W1);
  mm<0,0,0,LDW>(W0, W1, LDW, W1, LDW, nullptr, 0); l2g(P.Pw4,  W0);
  mm<0,0,0,LDW>(W1, W0, LDW, W0, LDW, nullptr, 0); l2g(P.Pw8,  W1);
  mm<0,0,0,LDW>(W0, W1, LDW, W1, LDW, nullptr, 0); l2g(P.Pw16, W0);  // C^16
  mm<0,0,0,LDW>(W1, W0, LDW, W0, LDW, nullptr, 0); l2g(P.Cpow32, W1);
  mm<0,0,0,LDW>(W2, W1, LDW, W1, LDW, nullptr, 0); l2g(P.Pw64, W2);
  mm<0,0,0,LDW>(CH, W2, LDW, W2, LDW, nullptr, 0); l2g(P.Pw128, CH);
  mm<0,0,0,LDW>(W1, W0, LDW, P.Pw8, NN, nullptr, 0);          // C^24
  mm<0,0,0,LDW>(W0, W1, LDW, P.Pw4, NN, nullptr, 0);          // C^28
  mm<0,0,0,LDW>(W1, W0, LDW, P.Pw2, NN, nullptr, 0);          // C^30
  mm<0,0,0,LDW>(W0, W1, LDW, P.Css, NN, nullptr, 0);          // C^31
  l2g(P.Cpow31, W0);
  // F^32
  g2l(W0, P.Fss);
  mm<0,0,0,LDW>(W1, W0, LDW, W0, LDW, nullptr, 0);
  mm<0,0,0,LDW>(W0, W1, LDW, W1, LDW, nullptr, 0);
  mm<0,0,0,LDW>(W1, W0, LDW, W0, LDW, nullptr, 0);
  mm<0,0,0,LDW>(W0, W1, LDW, W1, LDW, nullptr, 0);
  mm<0,0,0,LDW>(W1, W0, LDW, W0, LDW, nullptr, 0);
  l2g(P.Fpow, W1);
  // ---- Stein solve: sPss - C sPss C' = fPss - C pPss C' (7 doublings) ----
  g2l(W1, P.Css);                                             // M
  g2l(W2, P.CsTss);                                           // M'
  g2l(W0, P.pPss);
  mm<0,0,0,LDW>(CH, W1, LDW, W0, LDW, nullptr, 0);            // C*pPss
  mm<0,0,2,LDW>(W0, CH, LDW, W2, LDW, fPssG, NN);             // X = fPss - (C pPss) C'
  for (int it = 0; it < 7; ++it) {
    mm<0,0,0,LDW>(CH, W1, LDW, W0, LDW, nullptr, 0);          // M*X
    mm<0,0,1,LDW>(W0, CH, LDW, W2, LDW, W0, LDW);             // X += (M X) M'
    mm<0,0,0,LDW>(CH, W1, LDW, W1, LDW, nullptr, 0);          // M^2
    copyW(W1, CH);
    mm<0,0,0,LDW>(CH, W2, LDW, W2, LDW, nullptr, 0);          // (M')^2
    copyW(W2, CH);
  }
  l2g(P.sPss, W0);
  rsub_store(P.E0g, fPssG, W0);                               // E0 = fPss - sPss
  if (tid == 0) { P.meta[0] = N0; P.metaF[1] = mabs; }
}

// parallel closed-form tail: sP_{T-1-k} = sPss + C^k E0 C'^k  (C^k by binary powering)
__global__ __launch_bounds__(256) void k1d(KP P) {
  __shared__ __align__(16) float W0[LDW*NN], W1[LDW*NN], W2[LDW*NN];
  const int k = blockIdx.x;
  float* dst = P.out_cov + (size_t)(P.T-1-k)*4096;
  if (k == 0) {
    const float* src = P.fP + (size_t)(P.meta[0]-1)*4096;
    for (int e = threadIdx.x*4; e < 4096; e += 1024)
      *(float4*)(dst+e) = *(const float4*)(src+e);
    return;
  }
  const float* pw[8] = {P.Css, P.Pw2, P.Pw4, P.Pw8, P.Pw16, P.Cpow32, P.Pw64, P.Pw128};
  int b = __ffs(k) - 1;
  g2l(W1, pw[b]);
  float* cur = W1; float* oth = W0;
  for (int j = b+1; j < 8; ++j) {
    if ((k >> j) & 1) {
      mm<0,0,0,LDW>(oth, pw[j], NN, cur, LDW, nullptr, 0);
      float* tmp = cur; cur = oth; oth = tmp;
    }
  }
  mm<0,0,0,LDW>(W2, cur, LDW, P.E0g, NN, nullptr, 0);         // M*E0
  mm<0,1,1,LDW>(oth, W2, LDW, cur, LDW, P.sPss, NN);          // + (M E0) M^T + sPss
  l2g(dst, oth);
}

// parallel per-prefix-t derived quantities (+ per-t logdet)
__global__ __launch_bounds__(256) void k1b(KP P) {
  __shared__ __align__(16) float W0[LDW*NN], W1[LDW*NN], CH[LDW*NN];
  __shared__ float part[64], invd[64];
  const int t = blockIdx.x;
  if (t >= P.meta[0]) return;
  g2l(W0, P.pP + (size_t)t*4096);
  mm<0,0,0,LDW>(W1, P.H, NN, W0, LDW, nullptr, 0);            // HP
  mm<0,0,1,LDW>(CH, W1, LDW, P.HT, NN, P.R, NN);              // S
  chol68<true>(CH, part, invd);
  if (threadIdx.x == 0) { float s=0.f; for (int j=0;j<64;++j) s += part[j]; P.ld_pref[t] = s; }
  tri_solve2(CH, invd, W1, W1);                               // X
  l2g_T(P.Kp + (size_t)t*4096, W1);
  if (threadIdx.x < 64) {
    float s = P.b[threadIdx.x];
    for (int k = 0; k < 64; ++k) s -= W1[k*LDW + threadIdx.x]*P.Hb[k];
    P.u_pref[t*64 + threadIdx.x] = s;
  }
  __syncthreads();
  set_id(W0); tri_solve2(CH, invd, W0, W0);                   // Sinv
  l2g(P.Sinvp + (size_t)t*4096, W0);
  mm<1,0,2,LDW>(W0, W1, LDW, P.HA, NN, P.A, NN);              // F_t
  l2g(P.Fp + (size_t)t*4096, W0);
  // C_t
  g2l(W0, P.fP + (size_t)t*4096);
  mm<0,0,0,LDW>(W1, P.A, NN, W0, LDW, nullptr, 0);            // AF
  g2l(CH, P.pP + (size_t)(t+1)*4096);
  chol68<false>(CH, part, invd);
  tri_solve2(CH, invd, W1, W1);                               // X2
  l2g(P.CsTp + (size_t)t*4096, W1);
  l2g_T(P.Cp + (size_t)t*4096, W1);
}

// sequential backward smoothed-cov prefix
__global__ __launch_bounds__(256) void k1c(KP P) {
  __shared__ __align__(16) float W0[LDW*NN], W1[LDW*NN];
  const int N0 = P.meta[0];
  float* cur = W0; float* oth = W1;
  g2l(cur, P.sPss);
  for (int t = N0-1; t >= 0; --t) {
    sub_lg(oth, cur, P.pP + (size_t)(t+1)*4096);
    mm<0,0,0,LDW>(cur, P.Cp + (size_t)t*4096, NN, oth, LDW, nullptr, 0);
    mm<0,0,1,LDW>(oth, cur, LDW, P.CsTp + (size_t)t*4096, NN, P.fP + (size_t)t*4096, NN);
    l2g(P.out_cov + (size_t)t*4096, oth);
    float* tmp = cur; cur = oth; oth = tmp;
  }
}

// fill steady middle region of smoothed covs
__global__ __launch_bounds__(256) void k4(KP P) {
  const int t = blockIdx.x;
  if (t < P.meta[0] || t >= P.T - N1CAP) return;
  float* dst = P.out_cov + (size_t)t*4096;
  for (int e = threadIdx.x*4; e < 4096; e += 1024)
    *(float4*)(dst+e) = *(const float4*)(P.sPss + e);
}

// forward mean scan: local pass (steady chunks, zero init)
__global__ __launch_bounds__(256) void k2a(KP P) {
  __shared__ float xv[64], gv[64], ty[64], red[256];
  const int c = blockIdx.x;
  const int N0 = P.meta[0];
  const int PB = (N0 + LCH - 1)/LCH;
  if (c < PB) return;
  const int tid = threadIdx.x;
  if (tid < 64) xv[tid] = 0.f;
  __syncthreads();
  for (int s = 0; s < LCH; ++s) {
    int t = c*LCH + s;
    if (tid < 64) ty[tid] = P.Y[(size_t)t*64+tid] - P.c[tid];
    __syncthreads();
    matvec256(gv, P.Kss, ty, P.uss, red);
    matvec256(xv, P.Fss, xv, gv, red);
  }
  if (tid < 64) P.u_chunk[c*64+tid] = xv[tid];
}

// forward mean scan: sequential prefix + chunk carries
__global__ __launch_bounds__(256) void k2b(KP P) {
  __shared__ float xv[64], gv[64], ty[64], hp[64], red[256];
  const int tid = threadIdx.x;
  const int N0 = P.meta[0];
  const int PB = (N0 + LCH - 1)/LCH;
  const int PE = PB*LCH;
  if (tid < 64) xv[tid] = P.pm0[tid];
  __syncthreads();
  matvec256(hp, P.H, xv, nullptr, red);
  if (tid < 64) ty[tid] = P.Y[tid] - hp[tid] - P.c[tid];
  __syncthreads();
  matvec256(xv, P.Kp, ty, xv, red);            // fm0 = pm0 + K0*r0
  if (tid < 64) P.fm[tid] = xv[tid];
  __syncthreads();
  for (int t = 1; t < PE; ++t) {
    const float* Kt = (t < N0) ? P.Kp + (size_t)t*4096 : P.Kss;
    const float* Ft = (t < N0) ? P.Fp + (size_t)t*4096 : P.Fss;
    const float* ut = (t < N0) ? P.u_pref + t*64 : P.uss;
    if (tid < 64) ty[tid] = P.Y[(size_t)t*64+tid] - P.c[tid];
    __syncthreads();
    matvec256(gv, Kt, ty, ut, red);
    matvec256(xv, Ft, xv, gv, red);
    if (tid < 64) P.fm[(size_t)t*64+tid] = xv[tid];
    __syncthreads();
  }
  for (int c = PB; c < P.NC; ++c) {
    if (tid < 64) P.startstate[c*64+tid] = xv[tid];
    __syncthreads();
    matvec256(xv, P.Fpow, xv, P.u_chunk + c*64, red);
  }
}

// forward mean scan: replay steady chunks with true start states
__global__ __launch_bounds__(256) void k2c(KP P) {
  __shared__ float xv[64], gv[64], ty[64], red[256];
  const int c = blockIdx.x;
  const int N0 = P.meta[0];
  const int PB = (N0 + LCH - 1)/LCH;
  if (c < PB) return;
  const int tid = threadIdx.x;
  if (tid < 64) xv[tid] = P.startstate[c*64+tid];
  __syncthreads();
  for (int s = 0; s < LCH; ++s) {
    int t = c*LCH + s;
    if (tid < 64) ty[tid] = P.Y[(size_t)t*64+tid] - P.c[tid];
    __syncthreads();
    matvec256(gv, P.Kss, ty, P.uss, red);
    matvec256(xv, P.Fss, xv, gv, red);
    if (tid < 64) P.fm[(size_t)t*64+tid] = xv[tid];
    __syncthreads();
  }
}

// log-likelihood terms (one wave per t) -> llbuf
__global__ __launch_bounds__(64) void k5(KP P) {
  __shared__ float pmv[64], rv[64];
  const int t = blockIdx.x;
  const int N0 = P.meta[0];
  const int r = threadIdx.x;
  float pm;
  if (t == 0) {
    pm = P.pm0[r];
  } else {
    pmv[r] = P.fm[(size_t)(t-1)*64 + r];
    __syncthreads();
    float s = P.b[r];
    const float* Ar = P.A + r*64;
    for (int k = 0; k < 64; k += 4)
      s += Ar[k]*pmv[k] + Ar[k+1]*pmv[k+1] + Ar[k+2]*pmv[k+2] + Ar[k+3]*pmv[k+3];
    pm = s;
    __syncthreads();
  }
  pmv[r] = pm; __syncthreads();
  float rr = P.Y[(size_t)t*64 + r] - P.c[r];
  const float* Hr = P.H + r*64;
  for (int k = 0; k < 64; ++k) rr -= Hr[k]*pmv[k];
  rv[r] = rr; __syncthreads();
  const float* Sv = ((t < N0) ? P.Sinvp + (size_t)t*4096 : P.Sinvss) + r*64;
  float wv = 0.f;
  for (int k = 0; k < 64; ++k) wv += Sv[k]*rv[k];
  float qq = rr*wv;
  #pragma unroll
  for (int off = 32; off > 0; off >>= 1) qq += __shfl_xor(qq, off, 64);
  if (r == 0) {
    float ldt = (t < N0) ? P.ld_pref[t] : P.metaF[0];
    P.llbuf[t] = -58.8120661250990555 - (double)ldt - 0.5*(double)qq;
  }
}

// backward mean scan: local pass
__global__ __launch_bounds__(256) void k3a(KP P) {
  __shared__ float sv[64], wv[64], vv[64], fmv[64], red[256];
  const int c = blockIdx.x;
  const int N0 = P.meta[0];
  const int PB = (N0 + LCH - 1)/LCH;
  if (c < PB) return;
  const int tid = threadIdx.x;
  if (tid < 64) sv[tid] = 0.f;
  __syncthreads();
  int hi = (c == P.NC-1) ? P.T-2 : c*LCH + LCH - 1;
  for (int t = hi; t >= c*LCH; --t) {
    if (tid < 64) fmv[tid] = P.fm[(size_t)t*64+tid];
    __syncthreads();
    matvec256(wv, P.A, fmv, P.b, red);
    if (tid < 64) vv[tid] = sv[tid] - wv[tid];
    __syncthreads();
    matvec256(sv, P.Css, vv, fmv, red);
  }
  if (tid < 64) P.ub_chunk[c*64+tid] = sv[tid];
}

// backward mean scan: carries + sequential prefix
__global__ __launch_bounds__(256) void k3b(KP P) {
  __shared__ float sv[64], wv[64], vv[64], fmv[64], red[256];
  const int tid = threadIdx.x;
  const int N0 = P.meta[0];
  const int PB = (N0 + LCH - 1)/LCH;
  const int PE = PB*LCH;
  if (tid < 64) {
    float v = P.fm[(size_t)(P.T-1)*64+tid];
    sv[tid] = v;
    P.out_mean[(size_t)(P.T-1)*64+tid] = v;
  }
  __syncthreads();
  for (int c = P.NC-1; c >= PB; --c) {
    if (tid < 64) P.endstate[c*64+tid] = sv[tid];
    __syncthreads();
    matvec256(sv, (c == P.NC-1) ? P.Cpow31 : P.Cpow32, sv, P.ub_chunk + c*64, red);
  }
  for (int t = PE-1; t >= 0; --t) {
    const float* Ct = (t < N0) ? P.Cp + (size_t)t*4096 : P.Css;
    if (tid < 64) fmv[tid] = P.fm[(size_t)t*64+tid];
    __syncthreads();
    matvec256(wv, P.A, fmv, P.b, red);
    if (tid < 64) vv[tid] = sv[tid] - wv[tid];
    __syncthreads();
    matvec256(sv, Ct, vv, fmv, red);
    if (tid < 64) P.out_mean[(size_t)t*64+tid] = sv[tid];
    __syncthreads();
  }
}

// backward mean scan: replay steady chunks
__global__ __launch_bounds__(256) void k3c(KP P) {
  __shared__ float sv[64], wv[64], vv[64], fmv[64], red[256];
  const int c = blockIdx.x;
  const int N0 = P.meta[0];
  const int PB = (N0 + LCH - 1)/LCH;
  if (c < PB) return;
  const int tid = threadIdx.x;
  if (tid < 64) sv[tid] = P.endstate[c*64+tid];
  __syncthreads();
  int hi = (c == P.NC-1) ? P.T-2 : c*LCH + LCH - 1;
  for (int t = hi; t >= c*LCH; --t) {
    if (tid < 64) fmv[tid] = P.fm[(size_t)t*64+tid];
    __syncthreads();
    matvec256(wv, P.A, fmv, P.b, red);
    if (tid < 64) vv[tid] = sv[tid] - wv[tid];
    __syncthreads();
    matvec256(sv, P.Css, vv, fmv, red);
    if (tid < 64) P.out_mean[(size_t)t*64+tid] = sv[tid];
    __syncthreads();
  }
}

// reduce per-t ll terms
__global__ __launch_bounds__(256) void k6(KP P) {
  __shared__ double rd[256];
  double s = 0.0;
  for (int t = threadIdx.x; t < P.T; t += 256) s += P.llbuf[t];
  rd[threadIdx.x] = s; __syncthreads();
  #pragma unroll
  for (int off = 128; off > 0; off >>= 1) {
    if ((int)threadIdx.x < off) rd[threadIdx.x] += rd[threadIdx.x + off];
    __syncthreads();
  }
  if (threadIdx.x == 0) P.out_ll[0] = (float)rd[0];
}

// ---------- host ----------

extern "C" void kernel_launch(void* const* d_in, const int* in_sizes, int n_in,
                              void* d_out, int out_size, void* d_ws, size_t ws_size,
                              hipStream_t stream) {
  (void)n_in; (void)out_size;
  KP P;
  P.Y   = (const float*)d_in[0];
  P.A   = (const float*)d_in[1];
  P.b   = (const float*)d_in[2];
  P.Q   = (const float*)d_in[3];
  P.H   = (const float*)d_in[4];
  P.c   = (const float*)d_in[5];
  P.R   = (const float*)d_in[6];
  P.pm0 = (const float*)d_in[7];
  P.P0  = (const float*)d_in[8];
  const int T = in_sizes[0] / 64;
  const int NC = T / LCH;
  P.T = T; P.NC = NC;

  float* out = (float*)d_out;
  P.out_mean = out;
  P.out_cov  = out + (size_t)T*64;
  P.out_ll   = out + (size_t)T*64 + (size_t)T*4096;

  float* w = (float*)d_ws;
  size_t off = 0;
  auto alloc = [&](size_t n) { float* p = w + off; off += n; return p; };
  P.meta   = (int*)alloc(8);
  P.metaF  = alloc(8);
  P.llbuf  = (double*)alloc((size_t)2*T);
  P.fm     = alloc((size_t)T*64);
  P.AT = alloc(4096); P.HT = alloc(4096); P.HA = alloc(4096); P.Hb = alloc(64);
  P.Fss = alloc(4096); P.Kss = alloc(4096); P.Sinvss = alloc(4096);
  P.Css = alloc(4096); P.CsTss = alloc(4096); P.pPss = alloc(4096); P.sPss = alloc(4096);
  P.Fpow = alloc(4096); P.Cpow32 = alloc(4096); P.Cpow31 = alloc(4096); P.uss = alloc(64);
  P.Pw2 = alloc(4096); P.Pw4 = alloc(4096); P.Pw8 = alloc(4096); P.Pw16 = alloc(4096);
  P.Pw64 = alloc(4096); P.Pw128 = alloc(4096);
  P.u_chunk = alloc((size_t)NC*64); P.startstate = alloc((size_t)NC*64);
  P.ub_chunk = alloc((size_t)NC*64); P.endstate = alloc((size_t)NC*64);
  P.E0g = alloc(4096);
  // prefix arrays sized by remaining workspace
  size_t fixed = off;
  size_t per_t = 7*4096 + 64 + 1;
  size_t total_f = ws_size / 4;
  long long avail = (long long)total_f - (long long)fixed - 4096 - 64;
  int cap = (avail > 0) ? (int)(avail / (long long)per_t) : 8;
  if (cap > N0MAX) cap = N0MAX;
  if (cap < 8) cap = 8;
  P.N0cap = cap;
  P.ld_pref = alloc(cap);
  P.u_pref  = alloc((size_t)cap*64);
  P.fP    = alloc((size_t)cap*4096);
  P.pP    = alloc((size_t)(cap+1)*4096);
  P.Kp    = alloc((size_t)cap*4096);
  P.Sinvp = alloc((size_t)cap*4096);
  P.Fp    = alloc((size_t)cap*4096);
  P.Cp    = alloc((size_t)cap*4096);
  P.CsTp  = alloc((size_t)cap*4096);

  k0<<<1, 256, 0, stream>>>(P);
  k1<<<1, 256, 0, stream>>>(P);
  k1b<<<cap, 256, 0, stream>>>(P);
  k1d<<<N1CAP, 256, 0, stream>>>(P);
  k4<<<T, 256, 0, stream>>>(P);
  k1c<<<1, 256, 0, stream>>>(P);
  k2a<<<NC, 256, 0, stream>>>(P);
  k2b<<<1, 256, 0, stream>>>(P);
  k2c<<<NC, 256, 0, stream>>>(P);
  k5<<<T, 64, 0, stream>>>(P);
  k3a<<<NC, 256, 0, stream>>>(P);
  k3b<<<1, 256, 0, stream>>>(P);
  k3c<<<NC, 256, 0, stream>>>(P);
  k6<<<1, 256, 0, stream>>>(P);
}